// Round 7
// baseline (541.183 us; speedup 1.0000x reference)
//
#include <hip/hip_runtime.h>

// Sizes (fixed):
// x: (8,256,64,64) f32 | w_adj: (18,256,1,1) | b_adj: (18)
// w_off: (18,1,3,3) | b_off: (18) | w_def: (256,256,3,3)
// out: (8,256,64,64) f32
//
// Implicit GEMM: out[cout][pix] = sum_{K=tap*256+c} W[cout][K] * col[K][pix]
// M=256, N=32768, K=2304 -> 38.7 GFLOP -> bf16 MFMA.
// Round 7: split-K x3 over taps (3 taps per split) -> grid 1536 = 6 blocks/CU
// (was 512 = 2/CU, both pipes <35% busy, stall-bound). fp32 partials + k_add.
//
// ws layout (bytes):
//   xchan f32 : [0,        2359296)
//   off   f32 : [2359296,  4718592)
//   wfrag bf16: [4718592,  5898240)
//   xT    bf16: [5898240,  22675456)    8n x 4096pix x 256c
//   part  f32 : [22675456, 123338752)   3 x 8,388,608
// Fallback (ws too small): fp32 path, w_t f32 at [4718592, 7077888).

typedef __attribute__((ext_vector_type(8))) short short8v;
typedef __attribute__((ext_vector_type(4))) float f32x4;

#define NPLANE 4096

__device__ inline unsigned bf16_1(float a) {
    unsigned u = __float_as_uint(a);
    u += 0x7fffu + ((u >> 16) & 1u);
    return u >> 16;
}
__device__ inline unsigned bf16_pair(float a, float b) {
    unsigned ua = __float_as_uint(a); ua += 0x7fffu + ((ua >> 16) & 1u);
    unsigned ub = __float_as_uint(b); ub += 0x7fffu + ((ub >> 16) & 1u);
    return (ua >> 16) | (ub & 0xffff0000u);
}
__device__ inline float bl(unsigned u) { return __uint_as_float(u << 16); }
__device__ inline float bh(unsigned u) { return __uint_as_float(u & 0xffff0000u); }

// ---------------- 1x1 conv: split-K over 8 channel groups ----------------
__global__ __launch_bounds__(256) void k_xchan(const float* __restrict__ x,
                                               const float* __restrict__ w_adj,
                                               const float* __restrict__ b_adj,
                                               float* __restrict__ xchan) {
    __shared__ float wsh[256][18];
    __shared__ float part[8][32][19];
    int t = threadIdx.x;
    for (int i = t; i < 18 * 256; i += 256) {
        int o = i >> 8, c = i & 255;
        wsh[c][o] = w_adj[i];
    }
    __syncthreads();
    int n    = blockIdx.x >> 7;
    int pix0 = (blockIdx.x & 127) << 5;
    int p = t & 31, g = t >> 5;
    const float* xp = x + ((size_t)n << 20) + ((size_t)g << 17) + pix0 + p;
    float acc[18];
#pragma unroll
    for (int o = 0; o < 18; ++o) acc[o] = 0.f;
#pragma unroll 4
    for (int ci = 0; ci < 32; ++ci) {
        float xv = xp[(size_t)ci << 12];
        const float* wr = wsh[(g << 5) + ci];
#pragma unroll
        for (int o = 0; o < 18; ++o) acc[o] = fmaf(xv, wr[o], acc[o]);
    }
#pragma unroll
    for (int o = 0; o < 18; ++o) part[g][p][o] = acc[o];
    __syncthreads();
    for (int i = t; i < 576; i += 256) {
        int o = i >> 5, p2 = i & 31;
        float s = b_adj[o];
#pragma unroll
        for (int g2 = 0; g2 < 8; ++g2) s += part[g2][p2][o];
        xchan[((size_t)n * 18 + o) * NPLANE + pix0 + p2] = s;
    }
}

// ---------------- depthwise 3x3 (groups=18), pad=1 ----------------
__global__ __launch_bounds__(256) void k_off(const float* __restrict__ xchan,
                                             const float* __restrict__ w_off,
                                             const float* __restrict__ b_off,
                                             float* __restrict__ off) {
    int idx = blockIdx.x * 256 + threadIdx.x;
    int pix = idx & 4095;
    int w = pix & 63, h = pix >> 6;
    int rest = idx >> 12;
    int oc = rest % 18;
    const float* wp  = w_off + oc * 9;
    const float* src = xchan + (idx & ~4095);
    float acc = b_off[oc];
#pragma unroll
    for (int i = 0; i < 3; ++i) {
        int hh = h - 1 + i;
        if ((unsigned)hh >= 64u) continue;
#pragma unroll
        for (int j = 0; j < 3; ++j) {
            int ww = w - 1 + j;
            if ((unsigned)ww >= 64u) continue;
            acc = fmaf(src[(hh << 6) + ww], wp[i * 3 + j], acc);
        }
    }
    off[idx] = acc;
}

// ---------------- weight -> MFMA A-fragment layout (bf16) ----------------
// wfrag element idx = ((kstep*16 + ct)*64 + lane)*8 + e
// cout = ct*16 + (lane&15); c = (kstep&7)*32 + (lane>>4)*8 + e; tap = kstep>>3
__global__ __launch_bounds__(256) void k_wfrag(const float* __restrict__ w_def,
                                               ushort* __restrict__ wfrag) {
    int idx = blockIdx.x * 256 + threadIdx.x;   // over 589824
    int e     = idx & 7;
    int lane  = (idx >> 3) & 63;
    int ct    = (idx >> 9) & 15;
    int kstep = idx >> 13;
    int cout = ct * 16 + (lane & 15);
    int c    = ((kstep & 7) << 5) + ((lane >> 4) << 3) + e;
    int tap  = kstep >> 3;
    float v = w_def[cout * 2304 + c * 9 + tap];
    wfrag[idx] = (ushort)bf16_1(v);
}

// ---------------- transpose: x (n,c,pix) f32 -> xT (n,pix,c) bf16 --------
// XCD-aware: n in LOW 3 bits of blockIdx so image n is written by XCD n.
__global__ __launch_bounds__(256) void k_trans(const float* __restrict__ x,
                                               ushort* __restrict__ xT) {
    __shared__ unsigned tileU[64][35];
    int b  = blockIdx.x;
    int n  = b & 7;
    int cg = (b >> 3) & 3;
    int pg = b >> 5;
    int t  = threadIdx.x;
    int pl = t & 63, c4 = t >> 6;
    const float* src = x + (((size_t)(n * 256 + cg * 64 + c4 * 16)) << 12)
                         + (pg << 6) + pl;
#pragma unroll
    for (int i2 = 0; i2 < 8; ++i2) {
        float f0 = src[(size_t)(2 * i2) << 12];
        float f1 = src[(size_t)(2 * i2 + 1) << 12];
        tileU[pl][c4 * 8 + i2] = bf16_pair(f0, f1);
    }
    __syncthreads();
    int cl2 = t & 31, pr = t >> 5;
    unsigned* dst = (unsigned*)xT;
#pragma unroll
    for (int i = 0; i < 8; ++i) {
        int p2 = pr + (i << 3);
        dst[((size_t)(n << 12) + (pg << 6) + p2) * 128 + (cg << 5) + cl2] =
            tileU[p2][cl2];
    }
}

// ---------------- fused sampler + MFMA GEMM, split-K x3 ----------------
// grid = 1536: n = b&7 (XCD), tq = (b>>3)&63, split = b>>9 (taps 3s..3s+2).
// block = 4 waves = 64 px x 256 couts over 24 ksteps -> fp32 partial.
__global__ __launch_bounds__(256, 6) void k_fused(const ushort* __restrict__ xT,
                                                  const float* __restrict__ off,
                                                  const ushort* __restrict__ wfrag,
                                                  float* __restrict__ part) {
    __shared__ ushort colS[2][4][64][8];   // 8 KB, double-buffered

    int t = threadIdx.x;
    int wv = t >> 6, lane = t & 63;
    int n     = blockIdx.x & 7;
    int tq    = (blockIdx.x >> 3) & 63;
    int split = blockIdx.x >> 9;           // 0..2
    const int ks0 = split * 24, ks1 = ks0 + 24;

    int plo  = lane & 15;
    int spix = (tq << 6) + (wv << 4) + plo;   // this thread's sample pixel
    int sc   = (lane >> 4) << 3;              // channel offset in 32-group
    int sy = spix >> 6, sx = spix & 63;

    const float* offn = off + (((size_t)n * 18) << 12) + spix;
    const ushort* xTn = xT + (((size_t)n) << 12) * 256;

    float w00, w01, w10, w11;
    unsigned oA, oB, oC, oD;    // element offsets into xTn for corner gathers

    auto tap_setup = [&](int tp) {
        float oyv = offn[(size_t)(2 * tp) << 12];
        float oxv = offn[(size_t)(2 * tp + 1) << 12];
        float py = (float)(sy - 1 + tp / 3) + oyv;
        float px = (float)(sx - 1 + tp % 3) + oxv;
        float fy = floorf(py), fx = floorf(px);
        int y0 = (int)fy, x0 = (int)fx;
        float wy1 = py - fy, wx1 = px - fx;
        float ay0 = ((unsigned)y0       < 64u) ? 1.f - wy1 : 0.f;
        float ay1 = ((unsigned)(y0 + 1) < 64u) ? wy1 : 0.f;
        float ax0 = ((unsigned)x0       < 64u) ? 1.f - wx1 : 0.f;
        float ax1 = ((unsigned)(x0 + 1) < 64u) ? wx1 : 0.f;
        w00 = ay0 * ax0; w01 = ay0 * ax1; w10 = ay1 * ax0; w11 = ay1 * ax1;
        int yc0 = min(max(y0, 0), 63), yc1 = min(max(y0 + 1, 0), 63);
        int xc0 = min(max(x0, 0), 63), xc1 = min(max(x0 + 1, 0), 63);
        oA = (unsigned)((((yc0 << 6) + xc0) << 8) + sc);
        oB = (unsigned)((((yc0 << 6) + xc1) << 8) + sc);
        oC = (unsigned)((((yc1 << 6) + xc0) << 8) + sc);
        oD = (unsigned)((((yc1 << 6) + xc1) << 8) + sc);
    };

    auto interp_write = [&](int nb, uint4 A, uint4 B, uint4 C, uint4 D) {
        unsigned qa[4] = {A.x, A.y, A.z, A.w};
        unsigned qb[4] = {B.x, B.y, B.z, B.w};
        unsigned qc[4] = {C.x, C.y, C.z, C.w};
        unsigned qd[4] = {D.x, D.y, D.z, D.w};
        unsigned rr[4];
#pragma unroll
        for (int i = 0; i < 4; ++i) {
            float v0 = w00 * bl(qa[i]) + w01 * bl(qb[i]) +
                       w10 * bl(qc[i]) + w11 * bl(qd[i]);
            float v1 = w00 * bh(qa[i]) + w01 * bh(qb[i]) +
                       w10 * bh(qc[i]) + w11 * bh(qd[i]);
            rr[i] = bf16_pair(v0, v1);
        }
        *(uint4*)&colS[nb][wv][lane][0] = make_uint4(rr[0], rr[1], rr[2], rr[3]);
    };

    f32x4 acc[4][4] = {};

    // prologue: sample kstep ks0 into buffer 0 (ks0 is even); preload B-frags
    tap_setup(ks0 >> 3);
    {
        uint4 A = *(const uint4*)(xTn + oA);
        uint4 B = *(const uint4*)(xTn + oB);
        uint4 C = *(const uint4*)(xTn + oC);
        uint4 D = *(const uint4*)(xTn + oD);
        interp_write(ks0 & 1, A, B, C, D);
    }
    short8v bbC[4];
    {
        const ushort* wbk0 = wfrag + ((size_t)ks0 * 16 + (wv << 2)) * 512
                                    + (lane << 3);
#pragma unroll
        for (int j = 0; j < 4; ++j)
            bbC[j] = *(const short8v*)(wbk0 + (size_t)j * 512);
    }
    __syncthreads();

#pragma unroll 1
    for (int ks = ks0; ks < ks1; ++ks) {
        const int cur = ks & 1;
        const bool have = (ks + 1 < ks1);
        // 1. issue gathers for ks+1
        uint4 A = {0,0,0,0}, B = {0,0,0,0}, C = {0,0,0,0}, D = {0,0,0,0};
        if (have) {
            int kn = ks + 1;
            if ((kn & 7) == 0) tap_setup(kn >> 3);   // new tap corners
            unsigned d = (unsigned)((kn & 7) << 5);
            A = *(const uint4*)(xTn + oA + d);
            B = *(const uint4*)(xTn + oB + d);
            C = *(const uint4*)(xTn + oC + d);
            D = *(const uint4*)(xTn + oD + d);
        }
        // 2. prefetch B-frags for ks+1 (register double-buffer)
        const int ksn = have ? ks + 1 : ks;
        const ushort* wbkN = wfrag + ((size_t)ksn * 16 + (wv << 2)) * 512
                                    + (lane << 3);
        short8v bbN[4];
#pragma unroll
        for (int j = 0; j < 4; ++j)
            bbN[j] = *(const short8v*)(wbkN + (size_t)j * 512);
        // 3. A-fragments from LDS
        short8v a[4];
#pragma unroll
        for (int i = 0; i < 4; ++i)
            a[i] = *(const short8v*)&colS[cur][i][lane][0];
        // 4. MFMA with current B-frags (already in registers)
#pragma unroll
        for (int i = 0; i < 4; ++i)
#pragma unroll
            for (int j = 0; j < 4; ++j)
                acc[i][j] = __builtin_amdgcn_mfma_f32_16x16x32_bf16(
                    bbC[j], a[i], acc[i][j], 0, 0, 0);
        // 5. interp + LDS write for ks+1
        if (have) interp_write(cur ^ 1, A, B, C, D);
        __syncthreads();
#pragma unroll
        for (int j = 0; j < 4; ++j) bbC[j] = bbN[j];
    }

    // epilogue: partial write. D layout: col=lane&15 (pix), row=(lane>>4)*4+r
    int cl = lane & 15;
    int ch = (lane >> 4) << 2;
    float* po = part + (size_t)split * 8388608 + ((size_t)n << 20);
#pragma unroll
    for (int i = 0; i < 4; ++i) {
        int pix = (tq << 6) + (i << 4) + cl;
#pragma unroll
        for (int j = 0; j < 4; ++j) {
            int cout = (wv << 6) + (j << 4) + ch;
            float* op = po + ((size_t)cout << 12) + pix;
#pragma unroll
            for (int rr = 0; rr < 4; ++rr) op[(size_t)rr << 12] = acc[i][j][rr];
        }
    }
}

// ---------------- sum 3 partials -> out ----------------
__global__ __launch_bounds__(256) void k_add(const float* __restrict__ part,
                                             float* __restrict__ out) {
    size_t i = ((size_t)blockIdx.x * 256 + threadIdx.x) << 2;   // float4 slots
    float4 a = *(const float4*)(part + i);
    float4 b = *(const float4*)(part + 8388608 + i);
    float4 c = *(const float4*)(part + 16777216 + i);
    float4 r;
    r.x = a.x + b.x + c.x;
    r.y = a.y + b.y + c.y;
    r.z = a.z + b.z + c.z;
    r.w = a.w + b.w + c.w;
    *(float4*)(out + i) = r;
}

// ================= fallback fp32 path (ws too small) =================
__global__ __launch_bounds__(256) void k_reorder(const float* __restrict__ w_def,
                                                 float* __restrict__ w_t) {
    int idx = blockIdx.x * 256 + threadIdx.x;
    int co = idx & 255;
    int c  = (idx >> 8) & 255;
    int k  = idx >> 16;
    w_t[idx] = w_def[co * 2304 + c * 9 + k];
}

__global__ __launch_bounds__(256) void k_deform(const float* __restrict__ x,
                                                const float* __restrict__ off,
                                                const float* __restrict__ w_t,
                                                float* __restrict__ out) {
    __shared__ float colS[16][64];
    __shared__ float wS[16][128];
    __shared__ int   sy0[64], sx0[64];
    __shared__ float swy[64], swx[64];
    int t   = threadIdx.x;
    int n   = blockIdx.x >> 6;
    int h   = blockIdx.x & 63;
    int co0 = blockIdx.y << 7;
    float acc[4][8];
#pragma unroll
    for (int i = 0; i < 4; ++i)
#pragma unroll
        for (int j = 0; j < 8; ++j) acc[i][j] = 0.f;
    int tp = t & 15, tc = t >> 4;
    int cc_b = t >> 4, p0_b = (t & 15) << 2;
    const float* xn = x + (n << 20);
    for (int k = 0; k < 9; ++k) {
        if (t < 64) {
            const float* offp = off + ((n * 18 + 2 * k) << 12) + (h << 6);
            float oyv = offp[t];
            float oxv = offp[4096 + t];
            float py = (float)(h - 1 + k / 3) + oyv;
            float px = (float)(t - 1 + k % 3) + oxv;
            float fy = floorf(py), fx = floorf(px);
            sy0[t] = (int)fy; sx0[t] = (int)fx;
            swy[t] = py - fy; swx[t] = px - fx;
        }
        for (int c0 = 0; c0 < 256; c0 += 16) {
            __syncthreads();
            const float* base = xn + ((c0 + cc_b) << 12);
#pragma unroll
            for (int u = 0; u < 4; ++u) {
                int p = p0_b + u;
                int y0 = sy0[p], x0 = sx0[p];
                float wy = swy[p], wx = swx[p];
                float v00 = 0.f, v01 = 0.f, v10 = 0.f, v11 = 0.f;
                bool oky0 = (unsigned)y0 < 64u, oky1 = (unsigned)(y0 + 1) < 64u;
                bool okx0 = (unsigned)x0 < 64u, okx1 = (unsigned)(x0 + 1) < 64u;
                int r0 = (y0 << 6) + x0;
                if (oky0 && okx0) v00 = base[r0];
                if (oky0 && okx1) v01 = base[r0 + 1];
                if (oky1 && okx0) v10 = base[r0 + 64];
                if (oky1 && okx1) v11 = base[r0 + 65];
                colS[cc_b][p] = (v00 * (1.f - wx) + v01 * wx) * (1.f - wy) +
                                (v10 * (1.f - wx) + v11 * wx) * wy;
            }
            const float* wt = w_t + (k << 16) + (c0 << 8) + co0;
#pragma unroll
            for (int i = 0; i < 2; ++i) {
                int fi = i * 256 + t;
                int cc = fi >> 5;
                int cf = (fi & 31) << 2;
                *(float4*)&wS[cc][cf] = *(const float4*)&wt[(cc << 8) + cf];
            }
            __syncthreads();
#pragma unroll
            for (int kk = 0; kk < 16; ++kk) {
                float4 cv = *(const float4*)&colS[kk][tp << 2];
                float4 w0 = *(const float4*)&wS[kk][tc << 3];
                float4 w1 = *(const float4*)&wS[kk][(tc << 3) + 4];
                float cva[4] = {cv.x, cv.y, cv.z, cv.w};
                float wa[8]  = {w0.x, w0.y, w0.z, w0.w, w1.x, w1.y, w1.z, w1.w};
#pragma unroll
                for (int i = 0; i < 4; ++i)
#pragma unroll
                    for (int j = 0; j < 8; ++j)
                        acc[i][j] = fmaf(cva[i], wa[j], acc[i][j]);
            }
        }
    }
    int ob = (n << 20) + ((co0 + (tc << 3)) << 12) + (h << 6) + (tp << 2);
#pragma unroll
    for (int j = 0; j < 8; ++j) {
        float4 v = {acc[0][j], acc[1][j], acc[2][j], acc[3][j]};
        *(float4*)&out[ob + (j << 12)] = v;
    }
}

extern "C" void kernel_launch(void* const* d_in, const int* in_sizes, int n_in,
                              void* d_out, int out_size, void* d_ws, size_t ws_size,
                              hipStream_t stream) {
    const float* x     = (const float*)d_in[0];
    const float* w_adj = (const float*)d_in[1];
    const float* b_adj = (const float*)d_in[2];
    const float* w_off = (const float*)d_in[3];
    const float* b_off = (const float*)d_in[4];
    const float* w_def = (const float*)d_in[5];
    float* out = (float*)d_out;

    char* ws = (char*)d_ws;
    float* xchan = (float*)ws;                          // 2359296 B
    float* off   = (float*)(ws + 2359296);              // 2359296 B

    k_xchan<<<1024, 256, 0, stream>>>(x, w_adj, b_adj, xchan);
    k_off<<<2304, 256, 0, stream>>>(xchan, w_off, b_off, off);

    const size_t NEED = 123338752;
    if (ws_size >= NEED) {
        ushort* wfrag = (ushort*)(ws + 4718592);        // 1179648 B
        ushort* xT    = (ushort*)(ws + 5898240);        // 16777216 B
        float*  part  = (float*)(ws + 22675456);        // 100663296 B
        k_wfrag<<<2304, 256, 0, stream>>>(w_def, wfrag);
        k_trans<<<2048, 256, 0, stream>>>(x, xT);
        k_fused<<<1536, 256, 0, stream>>>(xT, off, wfrag, part);
        k_add<<<8192, 256, 0, stream>>>(part, out);
    } else {
        float* w_t = (float*)(ws + 4718592);
        k_reorder<<<2304, 256, 0, stream>>>(w_def, w_t);
        k_deform<<<dim3(512, 2), 256, 0, stream>>>(x, off, w_t, out);
    }
}

// Round 8
// 171.686 us; speedup vs baseline: 3.1522x; 3.1522x over previous
//
#include <hip/hip_runtime.h>

// Sizes (fixed):
// x: (8,256,64,64) f32 | w_adj: (18,256,1,1) | b_adj: (18)
// w_off: (18,1,3,3) | b_off: (18) | w_def: (256,256,3,3)
// out: (8,256,64,64) f32
//
// Implicit GEMM: out[cout][pix] = sum_{K=tap*256+c} W[cout][K] * col[K][pix]
// M=256, N=32768, K=2304 -> 38.7 GFLOP -> bf16 MFMA.
// Round 8: cout-split x2 (block = 64px x 128 couts), grid 1024 = 4 blocks/CU
// = 16 waves/CU (round 6 was 2 blocks/CU, both pipes <35% busy). No forced
// VGPR cap (round 7's launch_bounds(256,6) spilled acc -> 2.4 GB scratch).
// Sampling duplicated x2 per pixel (cheap VALU) but NO partials / k_add.
//
// ws layout (bytes):
//   xchan f32 : [0,        2359296)
//   off   f32 : [2359296,  4718592)
//   wfrag bf16: [4718592,  5898240)
//   xT    bf16: [5898240,  22675456)    8n x 4096pix x 256c
// Fallback (ws too small): fp32 path, w_t f32 at [4718592, 7077888).

typedef __attribute__((ext_vector_type(8))) short short8v;
typedef __attribute__((ext_vector_type(4))) float f32x4;

#define NPLANE 4096

__device__ inline unsigned bf16_1(float a) {
    unsigned u = __float_as_uint(a);
    u += 0x7fffu + ((u >> 16) & 1u);
    return u >> 16;
}
__device__ inline unsigned bf16_pair(float a, float b) {
    unsigned ua = __float_as_uint(a); ua += 0x7fffu + ((ua >> 16) & 1u);
    unsigned ub = __float_as_uint(b); ub += 0x7fffu + ((ub >> 16) & 1u);
    return (ua >> 16) | (ub & 0xffff0000u);
}
__device__ inline float bl(unsigned u) { return __uint_as_float(u << 16); }
__device__ inline float bh(unsigned u) { return __uint_as_float(u & 0xffff0000u); }

// ---------------- 1x1 conv: split-K over 8 channel groups ----------------
__global__ __launch_bounds__(256) void k_xchan(const float* __restrict__ x,
                                               const float* __restrict__ w_adj,
                                               const float* __restrict__ b_adj,
                                               float* __restrict__ xchan) {
    __shared__ float wsh[256][18];
    __shared__ float part[8][32][19];
    int t = threadIdx.x;
    for (int i = t; i < 18 * 256; i += 256) {
        int o = i >> 8, c = i & 255;
        wsh[c][o] = w_adj[i];
    }
    __syncthreads();
    int n    = blockIdx.x >> 7;
    int pix0 = (blockIdx.x & 127) << 5;
    int p = t & 31, g = t >> 5;
    const float* xp = x + ((size_t)n << 20) + ((size_t)g << 17) + pix0 + p;
    float acc[18];
#pragma unroll
    for (int o = 0; o < 18; ++o) acc[o] = 0.f;
#pragma unroll 4
    for (int ci = 0; ci < 32; ++ci) {
        float xv = xp[(size_t)ci << 12];
        const float* wr = wsh[(g << 5) + ci];
#pragma unroll
        for (int o = 0; o < 18; ++o) acc[o] = fmaf(xv, wr[o], acc[o]);
    }
#pragma unroll
    for (int o = 0; o < 18; ++o) part[g][p][o] = acc[o];
    __syncthreads();
    for (int i = t; i < 576; i += 256) {
        int o = i >> 5, p2 = i & 31;
        float s = b_adj[o];
#pragma unroll
        for (int g2 = 0; g2 < 8; ++g2) s += part[g2][p2][o];
        xchan[((size_t)n * 18 + o) * NPLANE + pix0 + p2] = s;
    }
}

// ---------------- depthwise 3x3 (groups=18), pad=1 ----------------
__global__ __launch_bounds__(256) void k_off(const float* __restrict__ xchan,
                                             const float* __restrict__ w_off,
                                             const float* __restrict__ b_off,
                                             float* __restrict__ off) {
    int idx = blockIdx.x * 256 + threadIdx.x;
    int pix = idx & 4095;
    int w = pix & 63, h = pix >> 6;
    int rest = idx >> 12;
    int oc = rest % 18;
    const float* wp  = w_off + oc * 9;
    const float* src = xchan + (idx & ~4095);
    float acc = b_off[oc];
#pragma unroll
    for (int i = 0; i < 3; ++i) {
        int hh = h - 1 + i;
        if ((unsigned)hh >= 64u) continue;
#pragma unroll
        for (int j = 0; j < 3; ++j) {
            int ww = w - 1 + j;
            if ((unsigned)ww >= 64u) continue;
            acc = fmaf(src[(hh << 6) + ww], wp[i * 3 + j], acc);
        }
    }
    off[idx] = acc;
}

// ---------------- weight -> MFMA A-fragment layout (bf16) ----------------
// wfrag element idx = ((kstep*16 + ct)*64 + lane)*8 + e
// cout = ct*16 + (lane&15); c = (kstep&7)*32 + (lane>>4)*8 + e; tap = kstep>>3
__global__ __launch_bounds__(256) void k_wfrag(const float* __restrict__ w_def,
                                               ushort* __restrict__ wfrag) {
    int idx = blockIdx.x * 256 + threadIdx.x;   // over 589824
    int e     = idx & 7;
    int lane  = (idx >> 3) & 63;
    int ct    = (idx >> 9) & 15;
    int kstep = idx >> 13;
    int cout = ct * 16 + (lane & 15);
    int c    = ((kstep & 7) << 5) + ((lane >> 4) << 3) + e;
    int tap  = kstep >> 3;
    float v = w_def[cout * 2304 + c * 9 + tap];
    wfrag[idx] = (ushort)bf16_1(v);
}

// ---------------- transpose: x (n,c,pix) f32 -> xT (n,pix,c) bf16 --------
// XCD-aware: n in LOW 3 bits of blockIdx so image n is written by XCD n.
__global__ __launch_bounds__(256) void k_trans(const float* __restrict__ x,
                                               ushort* __restrict__ xT) {
    __shared__ unsigned tileU[64][35];
    int b  = blockIdx.x;
    int n  = b & 7;
    int cg = (b >> 3) & 3;
    int pg = b >> 5;
    int t  = threadIdx.x;
    int pl = t & 63, c4 = t >> 6;
    const float* src = x + (((size_t)(n * 256 + cg * 64 + c4 * 16)) << 12)
                         + (pg << 6) + pl;
#pragma unroll
    for (int i2 = 0; i2 < 8; ++i2) {
        float f0 = src[(size_t)(2 * i2) << 12];
        float f1 = src[(size_t)(2 * i2 + 1) << 12];
        tileU[pl][c4 * 8 + i2] = bf16_pair(f0, f1);
    }
    __syncthreads();
    int cl2 = t & 31, pr = t >> 5;
    unsigned* dst = (unsigned*)xT;
#pragma unroll
    for (int i = 0; i < 8; ++i) {
        int p2 = pr + (i << 3);
        dst[((size_t)(n << 12) + (pg << 6) + p2) * 128 + (cg << 5) + cl2] =
            tileU[p2][cl2];
    }
}

// ---------------- fused sampler + MFMA GEMM, cout-split x2 ----------------
// grid = 1024: n = b&7 (XCD), tq = (b>>3)&63, chalf = b>>9 (couts chalf*128..).
// block = 4 waves = 64 px x 128 couts; wave = 64px(4 tiles) x 32co(2 tiles).
// acc[4][2] = 32 VGPR; natural register allocation (NO min-waves bound:
// round 7's (256,6) forced 40 VGPR and spilled acc to scratch).
__global__ __launch_bounds__(256) void k_fused(const ushort* __restrict__ xT,
                                               const float* __restrict__ off,
                                               const ushort* __restrict__ wfrag,
                                               float* __restrict__ out) {
    __shared__ ushort colS[2][4][64][8];   // 8 KB, double-buffered

    int t = threadIdx.x;
    int wv = t >> 6, lane = t & 63;
    int n     = blockIdx.x & 7;
    int tq    = (blockIdx.x >> 3) & 63;
    int chalf = blockIdx.x >> 9;           // 0..1
    const int ctb = (chalf << 3) + (wv << 1);   // this wave's base couttile

    int plo  = lane & 15;
    int spix = (tq << 6) + (wv << 4) + plo;   // this thread's sample pixel
    int sc   = (lane >> 4) << 3;              // channel offset in 32-group
    int sy = spix >> 6, sx = spix & 63;

    const float* offn = off + (((size_t)n * 18) << 12) + spix;
    const ushort* xTn = xT + (((size_t)n) << 12) * 256;

    float w00, w01, w10, w11;
    unsigned oA, oB, oC, oD;    // element offsets into xTn for corner gathers

    auto tap_setup = [&](int tp) {
        float oyv = offn[(size_t)(2 * tp) << 12];
        float oxv = offn[(size_t)(2 * tp + 1) << 12];
        float py = (float)(sy - 1 + tp / 3) + oyv;
        float px = (float)(sx - 1 + tp % 3) + oxv;
        float fy = floorf(py), fx = floorf(px);
        int y0 = (int)fy, x0 = (int)fx;
        float wy1 = py - fy, wx1 = px - fx;
        float ay0 = ((unsigned)y0       < 64u) ? 1.f - wy1 : 0.f;
        float ay1 = ((unsigned)(y0 + 1) < 64u) ? wy1 : 0.f;
        float ax0 = ((unsigned)x0       < 64u) ? 1.f - wx1 : 0.f;
        float ax1 = ((unsigned)(x0 + 1) < 64u) ? wx1 : 0.f;
        w00 = ay0 * ax0; w01 = ay0 * ax1; w10 = ay1 * ax0; w11 = ay1 * ax1;
        int yc0 = min(max(y0, 0), 63), yc1 = min(max(y0 + 1, 0), 63);
        int xc0 = min(max(x0, 0), 63), xc1 = min(max(x0 + 1, 0), 63);
        oA = (unsigned)((((yc0 << 6) + xc0) << 8) + sc);
        oB = (unsigned)((((yc0 << 6) + xc1) << 8) + sc);
        oC = (unsigned)((((yc1 << 6) + xc0) << 8) + sc);
        oD = (unsigned)((((yc1 << 6) + xc1) << 8) + sc);
    };

    auto interp_write = [&](int nb, uint4 A, uint4 B, uint4 C, uint4 D) {
        unsigned qa[4] = {A.x, A.y, A.z, A.w};
        unsigned qb[4] = {B.x, B.y, B.z, B.w};
        unsigned qc[4] = {C.x, C.y, C.z, C.w};
        unsigned qd[4] = {D.x, D.y, D.z, D.w};
        unsigned rr[4];
#pragma unroll
        for (int i = 0; i < 4; ++i) {
            float v0 = w00 * bl(qa[i]) + w01 * bl(qb[i]) +
                       w10 * bl(qc[i]) + w11 * bl(qd[i]);
            float v1 = w00 * bh(qa[i]) + w01 * bh(qb[i]) +
                       w10 * bh(qc[i]) + w11 * bh(qd[i]);
            rr[i] = bf16_pair(v0, v1);
        }
        *(uint4*)&colS[nb][wv][lane][0] = make_uint4(rr[0], rr[1], rr[2], rr[3]);
    };

    f32x4 acc[4][2] = {};

    // prologue: sample kstep 0 into buffer 0; preload B-frags for kstep 0
    tap_setup(0);
    {
        uint4 A = *(const uint4*)(xTn + oA);
        uint4 B = *(const uint4*)(xTn + oB);
        uint4 C = *(const uint4*)(xTn + oC);
        uint4 D = *(const uint4*)(xTn + oD);
        interp_write(0, A, B, C, D);
    }
    short8v bbC[2];
    {
        const ushort* wbk0 = wfrag + (size_t)ctb * 512 + (lane << 3);
#pragma unroll
        for (int j = 0; j < 2; ++j)
            bbC[j] = *(const short8v*)(wbk0 + (size_t)j * 512);
    }
    __syncthreads();

#pragma unroll 1
    for (int ks = 0; ks < 72; ++ks) {
        const int cur = ks & 1;
        const bool have = (ks < 71);
        // 1. issue gathers for ks+1
        uint4 A = {0,0,0,0}, B = {0,0,0,0}, C = {0,0,0,0}, D = {0,0,0,0};
        if (have) {
            int kn = ks + 1;
            if ((kn & 7) == 0) tap_setup(kn >> 3);   // new tap corners
            unsigned d = (unsigned)((kn & 7) << 5);
            A = *(const uint4*)(xTn + oA + d);
            B = *(const uint4*)(xTn + oB + d);
            C = *(const uint4*)(xTn + oC + d);
            D = *(const uint4*)(xTn + oD + d);
        }
        // 2. prefetch B-frags for ks+1 (register double-buffer)
        const int ksn = have ? ks + 1 : ks;
        const ushort* wbkN = wfrag + ((size_t)ksn * 16 + ctb) * 512
                                    + (lane << 3);
        short8v bbN[2];
#pragma unroll
        for (int j = 0; j < 2; ++j)
            bbN[j] = *(const short8v*)(wbkN + (size_t)j * 512);
        // 3. A-fragments from LDS
        short8v a[4];
#pragma unroll
        for (int i = 0; i < 4; ++i)
            a[i] = *(const short8v*)&colS[cur][i][lane][0];
        // 4. MFMA with current B-frags (already in registers)
#pragma unroll
        for (int i = 0; i < 4; ++i)
#pragma unroll
            for (int j = 0; j < 2; ++j)
                acc[i][j] = __builtin_amdgcn_mfma_f32_16x16x32_bf16(
                    bbC[j], a[i], acc[i][j], 0, 0, 0);
        // 5. interp + LDS write for ks+1
        if (have) interp_write(cur ^ 1, A, B, C, D);
        __syncthreads();
#pragma unroll
        for (int j = 0; j < 2; ++j) bbC[j] = bbN[j];
    }

    // epilogue: D layout col = lane&15 (pix), row = (lane>>4)*4 + r (cout)
    int cl = lane & 15;
    int ch = (lane >> 4) << 2;
    float* outn = out + ((size_t)n << 20);
#pragma unroll
    for (int i = 0; i < 4; ++i) {
        int pix = (tq << 6) + (i << 4) + cl;
#pragma unroll
        for (int j = 0; j < 2; ++j) {
            int cout = ((ctb + j) << 4) + ch;
            float* op = outn + ((size_t)cout << 12) + pix;
#pragma unroll
            for (int rr = 0; rr < 4; ++rr) op[(size_t)rr << 12] = acc[i][j][rr];
        }
    }
}

// ================= fallback fp32 path (ws too small) =================
__global__ __launch_bounds__(256) void k_reorder(const float* __restrict__ w_def,
                                                 float* __restrict__ w_t) {
    int idx = blockIdx.x * 256 + threadIdx.x;
    int co = idx & 255;
    int c  = (idx >> 8) & 255;
    int k  = idx >> 16;
    w_t[idx] = w_def[co * 2304 + c * 9 + k];
}

__global__ __launch_bounds__(256) void k_deform(const float* __restrict__ x,
                                                const float* __restrict__ off,
                                                const float* __restrict__ w_t,
                                                float* __restrict__ out) {
    __shared__ float colS[16][64];
    __shared__ float wS[16][128];
    __shared__ int   sy0[64], sx0[64];
    __shared__ float swy[64], swx[64];
    int t   = threadIdx.x;
    int n   = blockIdx.x >> 6;
    int h   = blockIdx.x & 63;
    int co0 = blockIdx.y << 7;
    float acc[4][8];
#pragma unroll
    for (int i = 0; i < 4; ++i)
#pragma unroll
        for (int j = 0; j < 8; ++j) acc[i][j] = 0.f;
    int tp = t & 15, tc = t >> 4;
    int cc_b = t >> 4, p0_b = (t & 15) << 2;
    const float* xn = x + (n << 20);
    for (int k = 0; k < 9; ++k) {
        if (t < 64) {
            const float* offp = off + ((n * 18 + 2 * k) << 12) + (h << 6);
            float oyv = offp[t];
            float oxv = offp[4096 + t];
            float py = (float)(h - 1 + k / 3) + oyv;
            float px = (float)(t - 1 + k % 3) + oxv;
            float fy = floorf(py), fx = floorf(px);
            sy0[t] = (int)fy; sx0[t] = (int)fx;
            swy[t] = py - fy; swx[t] = px - fx;
        }
        for (int c0 = 0; c0 < 256; c0 += 16) {
            __syncthreads();
            const float* base = xn + ((c0 + cc_b) << 12);
#pragma unroll
            for (int u = 0; u < 4; ++u) {
                int p = p0_b + u;
                int y0 = sy0[p], x0 = sx0[p];
                float wy = swy[p], wx = swx[p];
                float v00 = 0.f, v01 = 0.f, v10 = 0.f, v11 = 0.f;
                bool oky0 = (unsigned)y0 < 64u, oky1 = (unsigned)(y0 + 1) < 64u;
                bool okx0 = (unsigned)x0 < 64u, okx1 = (unsigned)(x0 + 1) < 64u;
                int r0 = (y0 << 6) + x0;
                if (oky0 && okx0) v00 = base[r0];
                if (oky0 && okx1) v01 = base[r0 + 1];
                if (oky1 && okx0) v10 = base[r0 + 64];
                if (oky1 && okx1) v11 = base[r0 + 65];
                colS[cc_b][p] = (v00 * (1.f - wx) + v01 * wx) * (1.f - wy) +
                                (v10 * (1.f - wx) + v11 * wx) * wy;
            }
            const float* wt = w_t + (k << 16) + (c0 << 8) + co0;
#pragma unroll
            for (int i = 0; i < 2; ++i) {
                int fi = i * 256 + t;
                int cc = fi >> 5;
                int cf = (fi & 31) << 2;
                *(float4*)&wS[cc][cf] = *(const float4*)&wt[(cc << 8) + cf];
            }
            __syncthreads();
#pragma unroll
            for (int kk = 0; kk < 16; ++kk) {
                float4 cv = *(const float4*)&colS[kk][tp << 2];
                float4 w0 = *(const float4*)&wS[kk][tc << 3];
                float4 w1 = *(const float4*)&wS[kk][(tc << 3) + 4];
                float cva[4] = {cv.x, cv.y, cv.z, cv.w};
                float wa[8]  = {w0.x, w0.y, w0.z, w0.w, w1.x, w1.y, w1.z, w1.w};
#pragma unroll
                for (int i = 0; i < 4; ++i)
#pragma unroll
                    for (int j = 0; j < 8; ++j)
                        acc[i][j] = fmaf(cva[i], wa[j], acc[i][j]);
            }
        }
    }
    int ob = (n << 20) + ((co0 + (tc << 3)) << 12) + (h << 6) + (tp << 2);
#pragma unroll
    for (int j = 0; j < 8; ++j) {
        float4 v = {acc[0][j], acc[1][j], acc[2][j], acc[3][j]};
        *(float4*)&out[ob + (j << 12)] = v;
    }
}

extern "C" void kernel_launch(void* const* d_in, const int* in_sizes, int n_in,
                              void* d_out, int out_size, void* d_ws, size_t ws_size,
                              hipStream_t stream) {
    const float* x     = (const float*)d_in[0];
    const float* w_adj = (const float*)d_in[1];
    const float* b_adj = (const float*)d_in[2];
    const float* w_off = (const float*)d_in[3];
    const float* b_off = (const float*)d_in[4];
    const float* w_def = (const float*)d_in[5];
    float* out = (float*)d_out;

    char* ws = (char*)d_ws;
    float* xchan = (float*)ws;                          // 2359296 B
    float* off   = (float*)(ws + 2359296);              // 2359296 B

    k_xchan<<<1024, 256, 0, stream>>>(x, w_adj, b_adj, xchan);
    k_off<<<2304, 256, 0, stream>>>(xchan, w_off, b_off, off);

    const size_t NEED = 22675456;
    if (ws_size >= NEED) {
        ushort* wfrag = (ushort*)(ws + 4718592);        // 1179648 B
        ushort* xT    = (ushort*)(ws + 5898240);        // 16777216 B
        k_wfrag<<<2304, 256, 0, stream>>>(w_def, wfrag);
        k_trans<<<2048, 256, 0, stream>>>(x, xT);
        k_fused<<<1024, 256, 0, stream>>>(xT, off, wfrag, out);
    } else {
        float* w_t = (float*)(ws + 4718592);
        k_reorder<<<2304, 256, 0, stream>>>(w_def, w_t);
        k_deform<<<dim3(512, 2), 256, 0, stream>>>(x, off, w_t, out);
    }
}

// Round 9
// 132.021 us; speedup vs baseline: 4.0992x; 1.3004x over previous
//
#include <hip/hip_runtime.h>

// Sizes (fixed):
// x: (8,256,64,64) f32 | w_adj: (18,256,1,1) | b_adj: (18)
// w_off: (18,1,3,3) | b_off: (18) | w_def: (256,256,3,3)
// out: (8,256,64,64) f32
//
// Implicit GEMM: out[cout][pix] = sum_{K=tap*256+c} W[cout][K] * col[K][pix]
// M=256, N=32768, K=2304 -> 38.7 GFLOP -> bf16 MFMA.
// Round 9: 32px x 256co blocks (NO sampling duplication - R8's x2 dup cost
// ~40us of VALU), grid 1024 = 4 blocks/CU / 16 waves/CU. 256 threads sample
// 2 ksteps per pass (ksp = t>>7) -> 1 barrier per 2 ksteps (36 total).
// Gathers issued 1 batch ahead; interp at top of batch (overlaps ds_read);
// weights register-rolled. Natural VGPR (~105), no launch_bounds cap (R7!).
//
// ws layout (bytes):
//   xchan f32 : [0,        2359296)
//   off   f32 : [2359296,  4718592)
//   wfrag bf16: [4718592,  5898240)
//   xT    bf16: [5898240,  22675456)    8n x 4096pix x 256c
// Fallback (ws too small): fp32 path, w_t f32 at [4718592, 7077888).

typedef __attribute__((ext_vector_type(8))) short short8v;
typedef __attribute__((ext_vector_type(4))) float f32x4;

#define NPLANE 4096

__device__ inline unsigned bf16_1(float a) {
    unsigned u = __float_as_uint(a);
    u += 0x7fffu + ((u >> 16) & 1u);
    return u >> 16;
}
__device__ inline unsigned bf16_pair(float a, float b) {
    unsigned ua = __float_as_uint(a); ua += 0x7fffu + ((ua >> 16) & 1u);
    unsigned ub = __float_as_uint(b); ub += 0x7fffu + ((ub >> 16) & 1u);
    return (ua >> 16) | (ub & 0xffff0000u);
}
__device__ inline float bl(unsigned u) { return __uint_as_float(u << 16); }
__device__ inline float bh(unsigned u) { return __uint_as_float(u & 0xffff0000u); }

// ---------------- 1x1 conv: split-K over 8 channel groups ----------------
__global__ __launch_bounds__(256) void k_xchan(const float* __restrict__ x,
                                               const float* __restrict__ w_adj,
                                               const float* __restrict__ b_adj,
                                               float* __restrict__ xchan) {
    __shared__ float wsh[256][18];
    __shared__ float part[8][32][19];
    int t = threadIdx.x;
    for (int i = t; i < 18 * 256; i += 256) {
        int o = i >> 8, c = i & 255;
        wsh[c][o] = w_adj[i];
    }
    __syncthreads();
    int n    = blockIdx.x >> 7;
    int pix0 = (blockIdx.x & 127) << 5;
    int p = t & 31, g = t >> 5;
    const float* xp = x + ((size_t)n << 20) + ((size_t)g << 17) + pix0 + p;
    float acc[18];
#pragma unroll
    for (int o = 0; o < 18; ++o) acc[o] = 0.f;
#pragma unroll 4
    for (int ci = 0; ci < 32; ++ci) {
        float xv = xp[(size_t)ci << 12];
        const float* wr = wsh[(g << 5) + ci];
#pragma unroll
        for (int o = 0; o < 18; ++o) acc[o] = fmaf(xv, wr[o], acc[o]);
    }
#pragma unroll
    for (int o = 0; o < 18; ++o) part[g][p][o] = acc[o];
    __syncthreads();
    for (int i = t; i < 576; i += 256) {
        int o = i >> 5, p2 = i & 31;
        float s = b_adj[o];
#pragma unroll
        for (int g2 = 0; g2 < 8; ++g2) s += part[g2][p2][o];
        xchan[((size_t)n * 18 + o) * NPLANE + pix0 + p2] = s;
    }
}

// ---------------- depthwise 3x3 (groups=18), pad=1 ----------------
__global__ __launch_bounds__(256) void k_off(const float* __restrict__ xchan,
                                             const float* __restrict__ w_off,
                                             const float* __restrict__ b_off,
                                             float* __restrict__ off) {
    int idx = blockIdx.x * 256 + threadIdx.x;
    int pix = idx & 4095;
    int w = pix & 63, h = pix >> 6;
    int rest = idx >> 12;
    int oc = rest % 18;
    const float* wp  = w_off + oc * 9;
    const float* src = xchan + (idx & ~4095);
    float acc = b_off[oc];
#pragma unroll
    for (int i = 0; i < 3; ++i) {
        int hh = h - 1 + i;
        if ((unsigned)hh >= 64u) continue;
#pragma unroll
        for (int j = 0; j < 3; ++j) {
            int ww = w - 1 + j;
            if ((unsigned)ww >= 64u) continue;
            acc = fmaf(src[(hh << 6) + ww], wp[i * 3 + j], acc);
        }
    }
    off[idx] = acc;
}

// ---------------- weight -> MFMA A-fragment layout (bf16) ----------------
// wfrag element idx = ((kstep*16 + ct)*64 + lane)*8 + e
// cout = ct*16 + (lane&15); c = (kstep&7)*32 + (lane>>4)*8 + e; tap = kstep>>3
__global__ __launch_bounds__(256) void k_wfrag(const float* __restrict__ w_def,
                                               ushort* __restrict__ wfrag) {
    int idx = blockIdx.x * 256 + threadIdx.x;   // over 589824
    int e     = idx & 7;
    int lane  = (idx >> 3) & 63;
    int ct    = (idx >> 9) & 15;
    int kstep = idx >> 13;
    int cout = ct * 16 + (lane & 15);
    int c    = ((kstep & 7) << 5) + ((lane >> 4) << 3) + e;
    int tap  = kstep >> 3;
    float v = w_def[cout * 2304 + c * 9 + tap];
    wfrag[idx] = (ushort)bf16_1(v);
}

// ---------------- transpose: x (n,c,pix) f32 -> xT (n,pix,c) bf16 --------
// XCD-aware: n in LOW 3 bits of blockIdx so image n is written by XCD n.
__global__ __launch_bounds__(256) void k_trans(const float* __restrict__ x,
                                               ushort* __restrict__ xT) {
    __shared__ unsigned tileU[64][35];
    int b  = blockIdx.x;
    int n  = b & 7;
    int cg = (b >> 3) & 3;
    int pg = b >> 5;
    int t  = threadIdx.x;
    int pl = t & 63, c4 = t >> 6;
    const float* src = x + (((size_t)(n * 256 + cg * 64 + c4 * 16)) << 12)
                         + (pg << 6) + pl;
#pragma unroll
    for (int i2 = 0; i2 < 8; ++i2) {
        float f0 = src[(size_t)(2 * i2) << 12];
        float f1 = src[(size_t)(2 * i2 + 1) << 12];
        tileU[pl][c4 * 8 + i2] = bf16_pair(f0, f1);
    }
    __syncthreads();
    int cl2 = t & 31, pr = t >> 5;
    unsigned* dst = (unsigned*)xT;
#pragma unroll
    for (int i = 0; i < 8; ++i) {
        int p2 = pr + (i << 3);
        dst[((size_t)(n << 12) + (pg << 6) + p2) * 128 + (cg << 5) + cl2] =
            tileU[p2][cl2];
    }
}

// ---------------- fused sampler + MFMA GEMM ----------------
// grid = 1024: n = b&7 (XCD), tq = b>>3 (0..127, 32-px tile).
// block = 4 waves; wave wv = 32 px x couts [wv*64, wv*64+64) -> acc[2][4].
// Sampling: thread t handles kstep parity ksp=t>>7 of each 2-kstep batch;
// within half: cg = (t>>5)&3 (8 channels), p = t&31 (pixel). One interp
// quad-set per thread per batch => NO duplication, half R8's VALU.
// Batch m uses LDS buf[m&1]; gathers for m+1 issued during m-1's MFMA phase,
// interp'd at top of m into buf[(m+1)&1]. One barrier per batch (36 total).
__global__ __launch_bounds__(256) void k_fused(const ushort* __restrict__ xT,
                                               const float* __restrict__ off,
                                               const ushort* __restrict__ wfrag,
                                               float* __restrict__ out) {
    __shared__ __align__(16) ushort colS[2][2][2][64][8];   // 8 KB: buf/ksp/tile/lane/e

    int t = threadIdx.x;
    int wv = t >> 6, lane = t & 63;
    int n  = blockIdx.x & 7;
    int tq = blockIdx.x >> 3;

    // sampling role
    int ksp = t >> 7;            // kstep parity within batch
    int r_  = t & 127;
    int cg  = r_ >> 5;           // channel group (8 ch)
    int p   = r_ & 31;           // pixel within 32-px tile
    int sc  = cg << 3;
    int spix = (tq << 5) + p;
    int sy = spix >> 6, sx = spix & 63;

    const float* offn = off + (((size_t)n * 18) << 12) + spix;
    const ushort* xTn = xT + (((size_t)n) << 12) * 256;

    // LDS write slots (per buffer)
    ushort* wp0 = &colS[0][ksp][p >> 4][(cg << 4) + (p & 15)][0];
    ushort* wp1 = &colS[1][ksp][p >> 4][(cg << 4) + (p & 15)][0];

    float w00, w01, w10, w11;
    unsigned oA, oB, oC, oD;     // element offsets into xTn (include sc)

    auto tap_setup = [&](int tp) {
        float oyv = offn[(size_t)(2 * tp) << 12];
        float oxv = offn[(size_t)(2 * tp + 1) << 12];
        int trow = (tp * 11) >> 5;           // tp/3 for 0..8
        int tcol = tp - trow * 3;
        float py = (float)(sy - 1 + trow) + oyv;
        float px = (float)(sx - 1 + tcol) + oxv;
        float fy = floorf(py), fx = floorf(px);
        int y0 = (int)fy, x0 = (int)fx;
        float wy1 = py - fy, wx1 = px - fx;
        float ay0 = ((unsigned)y0       < 64u) ? 1.f - wy1 : 0.f;
        float ay1 = ((unsigned)(y0 + 1) < 64u) ? wy1 : 0.f;
        float ax0 = ((unsigned)x0       < 64u) ? 1.f - wx1 : 0.f;
        float ax1 = ((unsigned)(x0 + 1) < 64u) ? wx1 : 0.f;
        w00 = ay0 * ax0; w01 = ay0 * ax1; w10 = ay1 * ax0; w11 = ay1 * ax1;
        int yc0 = min(max(y0, 0), 63), yc1 = min(max(y0 + 1, 0), 63);
        int xc0 = min(max(x0, 0), 63), xc1 = min(max(x0 + 1, 0), 63);
        oA = (unsigned)((((yc0 << 6) + xc0) << 8) + sc);
        oB = (unsigned)((((yc0 << 6) + xc1) << 8) + sc);
        oC = (unsigned)((((yc1 << 6) + xc0) << 8) + sc);
        oD = (unsigned)((((yc1 << 6) + xc1) << 8) + sc);
    };

    // gather set (single, register-resident across one batch)
    uint4 gA, gB, gC, gD;
    auto issue = [&](int m) {    // gathers for batch m (thread's kstep 2m+ksp)
        unsigned dd = (unsigned)(((2 * m + ksp) & 7) << 5);
        gA = *(const uint4*)(xTn + oA + dd);
        gB = *(const uint4*)(xTn + oB + dd);
        gC = *(const uint4*)(xTn + oC + dd);
        gD = *(const uint4*)(xTn + oD + dd);
    };
    auto interp_to = [&](ushort* wp) {
        unsigned qa[4] = {gA.x, gA.y, gA.z, gA.w};
        unsigned qb[4] = {gB.x, gB.y, gB.z, gB.w};
        unsigned qc[4] = {gC.x, gC.y, gC.z, gC.w};
        unsigned qd[4] = {gD.x, gD.y, gD.z, gD.w};
        unsigned rr[4];
#pragma unroll
        for (int i = 0; i < 4; ++i) {
            float v0 = w00 * bl(qa[i]) + w01 * bl(qb[i]) +
                       w10 * bl(qc[i]) + w11 * bl(qd[i]);
            float v1 = w00 * bh(qa[i]) + w01 * bh(qb[i]) +
                       w10 * bh(qc[i]) + w11 * bh(qd[i]);
            rr[i] = bf16_pair(v0, v1);
        }
        *(uint4*)wp = make_uint4(rr[0], rr[1], rr[2], rr[3]);
    };

    f32x4 acc[2][4] = {};
    const int ctb = wv << 2;     // wave's base couttile

    // weight fragment loader (4 couttiles for kstep ks)
    short8v bbC[4];
    auto loadW = [&](int ks, short8v* dst) {
        const ushort* wb = wfrag + ((size_t)ks * 16 + ctb) * 512 + (lane << 3);
#pragma unroll
        for (int j = 0; j < 4; ++j)
            dst[j] = *(const short8v*)(wb + (size_t)j * 512);
    };

    // ---- prologue: batch 0 data -> buf0; issue G(1); W(0) -> bbC ----
    tap_setup(0);
    issue(0);
    interp_to(wp0);
    issue(1);                    // tap still 0 (batch 1 = ksteps 2,3)
    loadW(0, bbC);
    __syncthreads();

    // ---- main loop: 36 batches (72 ksteps), 2x unrolled for static ph ----
    for (int bt2 = 0; bt2 < 18; ++bt2) {
#pragma unroll
        for (int ph = 0; ph < 2; ++ph) {
            const int bt = bt2 * 2 + ph;
            // (0) ds_read A-frags for this batch from buf[ph]
            const ushort* rb = &colS[ph][0][0][0][0];
            short8v a00 = *(const short8v*)(rb + ((0 * 64 + lane) << 3));
            short8v a01 = *(const short8v*)(rb + ((1 * 64 + lane) << 3));
            short8v a10 = *(const short8v*)(rb + ((2 * 64 + lane) << 3));
            short8v a11 = *(const short8v*)(rb + ((3 * 64 + lane) << 3));
            // (a) interp gathers (batch bt+1) -> buf[ph^1]   [VALU, overlaps]
            if (bt + 1 < 36) interp_to(ph ? wp0 : wp1);
            // (b) issue gathers for batch bt+2
            if (bt + 2 < 36) {
                if (((bt + 2) & 3) == 0) tap_setup((bt + 2) >> 2);
                issue(bt + 2);
            }
            // (c) weight-rolled MFMA: ksteps 2bt, 2bt+1
            short8v bbN[4];
            loadW(2 * bt + 1, bbN);
#pragma unroll
            for (int j = 0; j < 4; ++j) {
                acc[0][j] = __builtin_amdgcn_mfma_f32_16x16x32_bf16(
                    bbC[j], a00, acc[0][j], 0, 0, 0);
                acc[1][j] = __builtin_amdgcn_mfma_f32_16x16x32_bf16(
                    bbC[j], a01, acc[1][j], 0, 0, 0);
            }
            loadW(min(2 * bt + 2, 71), bbC);
#pragma unroll
            for (int j = 0; j < 4; ++j) {
                acc[0][j] = __builtin_amdgcn_mfma_f32_16x16x32_bf16(
                    bbN[j], a10, acc[0][j], 0, 0, 0);
                acc[1][j] = __builtin_amdgcn_mfma_f32_16x16x32_bf16(
                    bbN[j], a11, acc[1][j], 0, 0, 0);
            }
            // (d) barrier: buf[ph^1] writes done, buf[ph] reads done
            __syncthreads();
        }
    }

    // epilogue: D layout col = lane&15 (pix), row = (lane>>4)*4 + r (cout)
    int cl = lane & 15;
    int ch = (lane >> 4) << 2;
    float* outn = out + ((size_t)n << 20);
#pragma unroll
    for (int i = 0; i < 2; ++i) {
        int pix = (tq << 5) + (i << 4) + cl;
#pragma unroll
        for (int j = 0; j < 4; ++j) {
            int cout = ((ctb + j) << 4) + ch;
            float* op = outn + ((size_t)cout << 12) + pix;
#pragma unroll
            for (int rr = 0; rr < 4; ++rr) op[(size_t)rr << 12] = acc[i][j][rr];
        }
    }
}

// ================= fallback fp32 path (ws too small) =================
__global__ __launch_bounds__(256) void k_reorder(const float* __restrict__ w_def,
                                                 float* __restrict__ w_t) {
    int idx = blockIdx.x * 256 + threadIdx.x;
    int co = idx & 255;
    int c  = (idx >> 8) & 255;
    int k  = idx >> 16;
    w_t[idx] = w_def[co * 2304 + c * 9 + k];
}

__global__ __launch_bounds__(256) void k_deform(const float* __restrict__ x,
                                                const float* __restrict__ off,
                                                const float* __restrict__ w_t,
                                                float* __restrict__ out) {
    __shared__ float colS[16][64];
    __shared__ float wS[16][128];
    __shared__ int   sy0[64], sx0[64];
    __shared__ float swy[64], swx[64];
    int t   = threadIdx.x;
    int n   = blockIdx.x >> 6;
    int h   = blockIdx.x & 63;
    int co0 = blockIdx.y << 7;
    float acc[4][8];
#pragma unroll
    for (int i = 0; i < 4; ++i)
#pragma unroll
        for (int j = 0; j < 8; ++j) acc[i][j] = 0.f;
    int tp = t & 15, tc = t >> 4;
    int cc_b = t >> 4, p0_b = (t & 15) << 2;
    const float* xn = x + (n << 20);
    for (int k = 0; k < 9; ++k) {
        if (t < 64) {
            const float* offp = off + ((n * 18 + 2 * k) << 12) + (h << 6);
            float oyv = offp[t];
            float oxv = offp[4096 + t];
            float py = (float)(h - 1 + k / 3) + oyv;
            float px = (float)(t - 1 + k % 3) + oxv;
            float fy = floorf(py), fx = floorf(px);
            sy0[t] = (int)fy; sx0[t] = (int)fx;
            swy[t] = py - fy; swx[t] = px - fx;
        }
        for (int c0 = 0; c0 < 256; c0 += 16) {
            __syncthreads();
            const float* base = xn + ((c0 + cc_b) << 12);
#pragma unroll
            for (int u = 0; u < 4; ++u) {
                int p = p0_b + u;
                int y0 = sy0[p], x0 = sx0[p];
                float wy = swy[p], wx = swx[p];
                float v00 = 0.f, v01 = 0.f, v10 = 0.f, v11 = 0.f;
                bool oky0 = (unsigned)y0 < 64u, oky1 = (unsigned)(y0 + 1) < 64u;
                bool okx0 = (unsigned)x0 < 64u, okx1 = (unsigned)(x0 + 1) < 64u;
                int r0 = (y0 << 6) + x0;
                if (oky0 && okx0) v00 = base[r0];
                if (oky0 && okx1) v01 = base[r0 + 1];
                if (oky1 && okx0) v10 = base[r0 + 64];
                if (oky1 && okx1) v11 = base[r0 + 65];
                colS[cc_b][p] = (v00 * (1.f - wx) + v01 * wx) * (1.f - wy) +
                                (v10 * (1.f - wx) + v11 * wx) * wy;
            }
            const float* wt = w_t + (k << 16) + (c0 << 8) + co0;
#pragma unroll
            for (int i = 0; i < 2; ++i) {
                int fi = i * 256 + t;
                int cc = fi >> 5;
                int cf = (fi & 31) << 2;
                *(float4*)&wS[cc][cf] = *(const float4*)&wt[(cc << 8) + cf];
            }
            __syncthreads();
#pragma unroll
            for (int kk = 0; kk < 16; ++kk) {
                float4 cv = *(const float4*)&colS[kk][tp << 2];
                float4 w0 = *(const float4*)&wS[kk][tc << 3];
                float4 w1 = *(const float4*)&wS[kk][(tc << 3) + 4];
                float cva[4] = {cv.x, cv.y, cv.z, cv.w};
                float wa[8]  = {w0.x, w0.y, w0.z, w0.w, w1.x, w1.y, w1.z, w1.w};
#pragma unroll
                for (int i = 0; i < 4; ++i)
#pragma unroll
                    for (int j = 0; j < 8; ++j)
                        acc[i][j] = fmaf(cva[i], wa[j], acc[i][j]);
            }
        }
    }
    int ob = (n << 20) + ((co0 + (tc << 3)) << 12) + (h << 6) + (tp << 2);
#pragma unroll
    for (int j = 0; j < 8; ++j) {
        float4 v = {acc[0][j], acc[1][j], acc[2][j], acc[3][j]};
        *(float4*)&out[ob + (j << 12)] = v;
    }
}

extern "C" void kernel_launch(void* const* d_in, const int* in_sizes, int n_in,
                              void* d_out, int out_size, void* d_ws, size_t ws_size,
                              hipStream_t stream) {
    const float* x     = (const float*)d_in[0];
    const float* w_adj = (const float*)d_in[1];
    const float* b_adj = (const float*)d_in[2];
    const float* w_off = (const float*)d_in[3];
    const float* b_off = (const float*)d_in[4];
    const float* w_def = (const float*)d_in[5];
    float* out = (float*)d_out;

    char* ws = (char*)d_ws;
    float* xchan = (float*)ws;                          // 2359296 B
    float* off   = (float*)(ws + 2359296);              // 2359296 B

    k_xchan<<<1024, 256, 0, stream>>>(x, w_adj, b_adj, xchan);
    k_off<<<2304, 256, 0, stream>>>(xchan, w_off, b_off, off);

    const size_t NEED = 22675456;
    if (ws_size >= NEED) {
        ushort* wfrag = (ushort*)(ws + 4718592);        // 1179648 B
        ushort* xT    = (ushort*)(ws + 5898240);        // 16777216 B
        k_wfrag<<<2304, 256, 0, stream>>>(w_def, wfrag);
        k_trans<<<2048, 256, 0, stream>>>(x, xT);
        k_fused<<<1024, 256, 0, stream>>>(xT, off, wfrag, out);
    } else {
        float* w_t = (float*)(ws + 4718592);
        k_reorder<<<2304, 256, 0, stream>>>(w_def, w_t);
        k_deform<<<dim3(512, 2), 256, 0, stream>>>(x, off, w_t, out);
    }
}

// Round 10
// 104.912 us; speedup vs baseline: 5.1584x; 1.2584x over previous
//
#include <hip/hip_runtime.h>

// Sizes (fixed):
// x: (8,256,64,64) f32 | w_adj: (18,256,1,1) | b_adj: (18)
// w_off: (18,1,3,3) | b_off: (18) | w_def: (256,256,3,3)
// out: (8,256,64,64) f32
//
// Implicit GEMM: out[cout][pix] = sum_{K=tap*256+c} W[cout][K] * col[K][pix]
// M=256, N=32768, K=2304 -> 38.7 GFLOP -> bf16 MFMA.
// Round 10: (a) sampling lanes remapped to 16px x 4cg per wave so each
// corner-gather's 4 cgs share one 64B line (~16 lines/gather vs 32 -> 2x TA);
// (b) weight loads moved to batch top + 3rd rolling set (full-batch prefetch
// distance) so no L2 latency lands on the MFMA cluster.
//
// ws layout (bytes):
//   xchan f32 : [0,        2359296)
//   off   f32 : [2359296,  4718592)
//   wfrag bf16: [4718592,  5898240)
//   xT    bf16: [5898240,  22675456)    8n x 4096pix x 256c
// Fallback (ws too small): fp32 path, w_t f32 at [4718592, 7077888).

typedef __attribute__((ext_vector_type(8))) short short8v;
typedef __attribute__((ext_vector_type(4))) float f32x4;

#define NPLANE 4096

__device__ inline unsigned bf16_1(float a) {
    unsigned u = __float_as_uint(a);
    u += 0x7fffu + ((u >> 16) & 1u);
    return u >> 16;
}
__device__ inline unsigned bf16_pair(float a, float b) {
    unsigned ua = __float_as_uint(a); ua += 0x7fffu + ((ua >> 16) & 1u);
    unsigned ub = __float_as_uint(b); ub += 0x7fffu + ((ub >> 16) & 1u);
    return (ua >> 16) | (ub & 0xffff0000u);
}
__device__ inline float bl(unsigned u) { return __uint_as_float(u << 16); }
__device__ inline float bh(unsigned u) { return __uint_as_float(u & 0xffff0000u); }

// ---------------- 1x1 conv: split-K over 8 channel groups ----------------
__global__ __launch_bounds__(256) void k_xchan(const float* __restrict__ x,
                                               const float* __restrict__ w_adj,
                                               const float* __restrict__ b_adj,
                                               float* __restrict__ xchan) {
    __shared__ float wsh[256][18];
    __shared__ float part[8][32][19];
    int t = threadIdx.x;
    for (int i = t; i < 18 * 256; i += 256) {
        int o = i >> 8, c = i & 255;
        wsh[c][o] = w_adj[i];
    }
    __syncthreads();
    int n    = blockIdx.x >> 7;
    int pix0 = (blockIdx.x & 127) << 5;
    int p = t & 31, g = t >> 5;
    const float* xp = x + ((size_t)n << 20) + ((size_t)g << 17) + pix0 + p;
    float acc[18];
#pragma unroll
    for (int o = 0; o < 18; ++o) acc[o] = 0.f;
#pragma unroll 4
    for (int ci = 0; ci < 32; ++ci) {
        float xv = xp[(size_t)ci << 12];
        const float* wr = wsh[(g << 5) + ci];
#pragma unroll
        for (int o = 0; o < 18; ++o) acc[o] = fmaf(xv, wr[o], acc[o]);
    }
#pragma unroll
    for (int o = 0; o < 18; ++o) part[g][p][o] = acc[o];
    __syncthreads();
    for (int i = t; i < 576; i += 256) {
        int o = i >> 5, p2 = i & 31;
        float s = b_adj[o];
#pragma unroll
        for (int g2 = 0; g2 < 8; ++g2) s += part[g2][p2][o];
        xchan[((size_t)n * 18 + o) * NPLANE + pix0 + p2] = s;
    }
}

// ---------------- depthwise 3x3 (groups=18), pad=1 ----------------
__global__ __launch_bounds__(256) void k_off(const float* __restrict__ xchan,
                                             const float* __restrict__ w_off,
                                             const float* __restrict__ b_off,
                                             float* __restrict__ off) {
    int idx = blockIdx.x * 256 + threadIdx.x;
    int pix = idx & 4095;
    int w = pix & 63, h = pix >> 6;
    int rest = idx >> 12;
    int oc = rest % 18;
    const float* wp  = w_off + oc * 9;
    const float* src = xchan + (idx & ~4095);
    float acc = b_off[oc];
#pragma unroll
    for (int i = 0; i < 3; ++i) {
        int hh = h - 1 + i;
        if ((unsigned)hh >= 64u) continue;
#pragma unroll
        for (int j = 0; j < 3; ++j) {
            int ww = w - 1 + j;
            if ((unsigned)ww >= 64u) continue;
            acc = fmaf(src[(hh << 6) + ww], wp[i * 3 + j], acc);
        }
    }
    off[idx] = acc;
}

// ---------------- weight -> MFMA A-fragment layout (bf16) ----------------
// wfrag element idx = ((kstep*16 + ct)*64 + lane)*8 + e
// cout = ct*16 + (lane&15); c = (kstep&7)*32 + (lane>>4)*8 + e; tap = kstep>>3
__global__ __launch_bounds__(256) void k_wfrag(const float* __restrict__ w_def,
                                               ushort* __restrict__ wfrag) {
    int idx = blockIdx.x * 256 + threadIdx.x;   // over 589824
    int e     = idx & 7;
    int lane  = (idx >> 3) & 63;
    int ct    = (idx >> 9) & 15;
    int kstep = idx >> 13;
    int cout = ct * 16 + (lane & 15);
    int c    = ((kstep & 7) << 5) + ((lane >> 4) << 3) + e;
    int tap  = kstep >> 3;
    float v = w_def[cout * 2304 + c * 9 + tap];
    wfrag[idx] = (ushort)bf16_1(v);
}

// ---------------- transpose: x (n,c,pix) f32 -> xT (n,pix,c) bf16 --------
// XCD-aware: n in LOW 3 bits of blockIdx so image n is written by XCD n.
__global__ __launch_bounds__(256) void k_trans(const float* __restrict__ x,
                                               ushort* __restrict__ xT) {
    __shared__ unsigned tileU[64][35];
    int b  = blockIdx.x;
    int n  = b & 7;
    int cg = (b >> 3) & 3;
    int pg = b >> 5;
    int t  = threadIdx.x;
    int pl = t & 63, c4 = t >> 6;
    const float* src = x + (((size_t)(n * 256 + cg * 64 + c4 * 16)) << 12)
                         + (pg << 6) + pl;
#pragma unroll
    for (int i2 = 0; i2 < 8; ++i2) {
        float f0 = src[(size_t)(2 * i2) << 12];
        float f1 = src[(size_t)(2 * i2 + 1) << 12];
        tileU[pl][c4 * 8 + i2] = bf16_pair(f0, f1);
    }
    __syncthreads();
    int cl2 = t & 31, pr = t >> 5;
    unsigned* dst = (unsigned*)xT;
#pragma unroll
    for (int i = 0; i < 8; ++i) {
        int p2 = pr + (i << 3);
        dst[((size_t)(n << 12) + (pg << 6) + p2) * 128 + (cg << 5) + cl2] =
            tileU[p2][cl2];
    }
}

// ---------------- fused sampler + MFMA GEMM ----------------
// grid = 1024: n = b&7 (XCD), tq = b>>3 (0..127, 32-px tile).
// block = 4 waves; GEMM role: wave wv -> couttiles [4wv,4wv+4), acc[2][4].
// Sampling role: ksp = t>>7 (kstep parity), tile = (t>>6)&1 (pixtile),
//   pix = (t>>2)&15, cg = t&3  -> each WAVE covers 16 px x 4 cg, so one
//   corner-gather touches ~16 cache lines (4 cgs = one 64B line).
// Weights: bbA (cur ks0, prefetched last batch), bbB (cur ks1, loaded at
// batch top behind ds_read+interp), bbN (next ks0, loaded at batch top).
__global__ __launch_bounds__(256) void k_fused(const ushort* __restrict__ xT,
                                               const float* __restrict__ off,
                                               const ushort* __restrict__ wfrag,
                                               float* __restrict__ out) {
    __shared__ __align__(16) ushort colS[2][2][2][64][8];   // 8 KB: buf/ksp/tile/slot/e

    int t = threadIdx.x;
    int wv = t >> 6, lane = t & 63;
    int n  = blockIdx.x & 7;
    int tq = blockIdx.x >> 3;

    // sampling role
    int ksp  = t >> 7;               // kstep parity within batch
    int tile = (t >> 6) & 1;         // pixtile
    int pix  = (t >> 2) & 15;        // pixel within tile
    int cg   = t & 3;                // channel group (8 ch)
    int sc   = cg << 3;
    int spix = (tq << 5) + (tile << 4) + pix;
    int sy = spix >> 6, sx = spix & 63;

    const float* offn = off + (((size_t)n * 18) << 12) + spix;
    const ushort* xTn = xT + (((size_t)n) << 12) * 256;

    // LDS write slots: slot = (cg<<4)+pix is a bijection of lane -> 0..63
    ushort* wp0 = &colS[0][ksp][tile][(cg << 4) + pix][0];
    ushort* wp1 = &colS[1][ksp][tile][(cg << 4) + pix][0];

    float w00, w01, w10, w11;
    unsigned oA, oB, oC, oD;     // element offsets into xTn (include sc)

    auto tap_setup = [&](int tp) {
        float oyv = offn[(size_t)(2 * tp) << 12];
        float oxv = offn[(size_t)(2 * tp + 1) << 12];
        int trow = (tp * 11) >> 5;           // tp/3 for 0..8
        int tcol = tp - trow * 3;
        float py = (float)(sy - 1 + trow) + oyv;
        float px = (float)(sx - 1 + tcol) + oxv;
        float fy = floorf(py), fx = floorf(px);
        int y0 = (int)fy, x0 = (int)fx;
        float wy1 = py - fy, wx1 = px - fx;
        float ay0 = ((unsigned)y0       < 64u) ? 1.f - wy1 : 0.f;
        float ay1 = ((unsigned)(y0 + 1) < 64u) ? wy1 : 0.f;
        float ax0 = ((unsigned)x0       < 64u) ? 1.f - wx1 : 0.f;
        float ax1 = ((unsigned)(x0 + 1) < 64u) ? wx1 : 0.f;
        w00 = ay0 * ax0; w01 = ay0 * ax1; w10 = ay1 * ax0; w11 = ay1 * ax1;
        int yc0 = min(max(y0, 0), 63), yc1 = min(max(y0 + 1, 0), 63);
        int xc0 = min(max(x0, 0), 63), xc1 = min(max(x0 + 1, 0), 63);
        oA = (unsigned)((((yc0 << 6) + xc0) << 8) + sc);
        oB = (unsigned)((((yc0 << 6) + xc1) << 8) + sc);
        oC = (unsigned)((((yc1 << 6) + xc0) << 8) + sc);
        oD = (unsigned)((((yc1 << 6) + xc1) << 8) + sc);
    };

    // gather set (register-resident across one batch)
    uint4 gA, gB, gC, gD;
    auto issue = [&](int m) {    // gathers for batch m (thread's kstep 2m+ksp)
        unsigned dd = (unsigned)(((2 * m + ksp) & 7) << 5);
        gA = *(const uint4*)(xTn + oA + dd);
        gB = *(const uint4*)(xTn + oB + dd);
        gC = *(const uint4*)(xTn + oC + dd);
        gD = *(const uint4*)(xTn + oD + dd);
    };
    auto interp_to = [&](ushort* wp) {
        unsigned qa[4] = {gA.x, gA.y, gA.z, gA.w};
        unsigned qb[4] = {gB.x, gB.y, gB.z, gB.w};
        unsigned qc[4] = {gC.x, gC.y, gC.z, gC.w};
        unsigned qd[4] = {gD.x, gD.y, gD.z, gD.w};
        unsigned rr[4];
#pragma unroll
        for (int i = 0; i < 4; ++i) {
            float v0 = w00 * bl(qa[i]) + w01 * bl(qb[i]) +
                       w10 * bl(qc[i]) + w11 * bl(qd[i]);
            float v1 = w00 * bh(qa[i]) + w01 * bh(qb[i]) +
                       w10 * bh(qc[i]) + w11 * bh(qd[i]);
            rr[i] = bf16_pair(v0, v1);
        }
        *(uint4*)wp = make_uint4(rr[0], rr[1], rr[2], rr[3]);
    };

    f32x4 acc[2][4] = {};
    const int ctb = wv << 2;     // wave's base couttile

    short8v bbA[4], bbB[4], bbN[4];
    auto loadW = [&](int ks, short8v* dst) {
        const ushort* wb = wfrag + ((size_t)ks * 16 + ctb) * 512 + (lane << 3);
#pragma unroll
        for (int j = 0; j < 4; ++j)
            dst[j] = *(const short8v*)(wb + (size_t)j * 512);
    };

    // ---- prologue: batch 0 -> buf0; gathers for batch 1; W(0) -> bbA ----
    tap_setup(0);
    issue(0);
    interp_to(wp0);
    issue(1);                    // batch 1 = ksteps 2,3 (still tap 0)
    loadW(0, bbA);
    __syncthreads();

    // ---- main loop: 36 batches (72 ksteps), 2x unrolled for static ph ----
    for (int bt2 = 0; bt2 < 18; ++bt2) {
#pragma unroll
        for (int ph = 0; ph < 2; ++ph) {
            const int bt = bt2 * 2 + ph;
            // (0) ds_read A-frags for this batch from buf[ph]
            const ushort* rb = &colS[ph][0][0][0][0];
            short8v a00 = *(const short8v*)(rb + ((0 * 64 + lane) << 3));
            short8v a01 = *(const short8v*)(rb + ((1 * 64 + lane) << 3));
            short8v a10 = *(const short8v*)(rb + ((2 * 64 + lane) << 3));
            short8v a11 = *(const short8v*)(rb + ((3 * 64 + lane) << 3));
            // (1) weight loads early: cur ks1 + next-batch ks0 (L2 latency
            //     hides behind interp + first MFMA quad)
            loadW(2 * bt + 1, bbB);
            if (bt + 1 < 36) loadW(2 * bt + 2, bbN);
            // (2) interp gathers (batch bt+1) -> buf[ph^1]   [VALU]
            if (bt + 1 < 36) interp_to(ph ? wp0 : wp1);
            // (3) issue gathers for batch bt+2
            if (bt + 2 < 36) {
                if (((bt + 2) & 3) == 0) tap_setup((bt + 2) >> 2);
                issue(bt + 2);
            }
            // (4) MFMA: kstep 2bt with bbA, kstep 2bt+1 with bbB
#pragma unroll
            for (int j = 0; j < 4; ++j) {
                acc[0][j] = __builtin_amdgcn_mfma_f32_16x16x32_bf16(
                    bbA[j], a00, acc[0][j], 0, 0, 0);
                acc[1][j] = __builtin_amdgcn_mfma_f32_16x16x32_bf16(
                    bbA[j], a01, acc[1][j], 0, 0, 0);
            }
#pragma unroll
            for (int j = 0; j < 4; ++j) {
                acc[0][j] = __builtin_amdgcn_mfma_f32_16x16x32_bf16(
                    bbB[j], a10, acc[0][j], 0, 0, 0);
                acc[1][j] = __builtin_amdgcn_mfma_f32_16x16x32_bf16(
                    bbB[j], a11, acc[1][j], 0, 0, 0);
            }
            // (5) barrier: buf[ph^1] writes done, buf[ph] reads done
            __syncthreads();
#pragma unroll
            for (int j = 0; j < 4; ++j) bbA[j] = bbN[j];
        }
    }

    // epilogue: D layout col = lane&15 (pix), row = (lane>>4)*4 + r (cout)
    int cl = lane & 15;
    int ch = (lane >> 4) << 2;
    float* outn = out + ((size_t)n << 20);
#pragma unroll
    for (int i = 0; i < 2; ++i) {
        int opix = (tq << 5) + (i << 4) + cl;
#pragma unroll
        for (int j = 0; j < 4; ++j) {
            int cout = ((ctb + j) << 4) + ch;
            float* op = outn + ((size_t)cout << 12) + opix;
#pragma unroll
            for (int rr = 0; rr < 4; ++rr) op[(size_t)rr << 12] = acc[i][j][rr];
        }
    }
}

// ================= fallback fp32 path (ws too small) =================
__global__ __launch_bounds__(256) void k_reorder(const float* __restrict__ w_def,
                                                 float* __restrict__ w_t) {
    int idx = blockIdx.x * 256 + threadIdx.x;
    int co = idx & 255;
    int c  = (idx >> 8) & 255;
    int k  = idx >> 16;
    w_t[idx] = w_def[co * 2304 + c * 9 + k];
}

__global__ __launch_bounds__(256) void k_deform(const float* __restrict__ x,
                                                const float* __restrict__ off,
                                                const float* __restrict__ w_t,
                                                float* __restrict__ out) {
    __shared__ float colS[16][64];
    __shared__ float wS[16][128];
    __shared__ int   sy0[64], sx0[64];
    __shared__ float swy[64], swx[64];
    int t   = threadIdx.x;
    int n   = blockIdx.x >> 6;
    int h   = blockIdx.x & 63;
    int co0 = blockIdx.y << 7;
    float acc[4][8];
#pragma unroll
    for (int i = 0; i < 4; ++i)
#pragma unroll
        for (int j = 0; j < 8; ++j) acc[i][j] = 0.f;
    int tp = t & 15, tc = t >> 4;
    int cc_b = t >> 4, p0_b = (t & 15) << 2;
    const float* xn = x + (n << 20);
    for (int k = 0; k < 9; ++k) {
        if (t < 64) {
            const float* offp = off + ((n * 18 + 2 * k) << 12) + (h << 6);
            float oyv = offp[t];
            float oxv = offp[4096 + t];
            float py = (float)(h - 1 + k / 3) + oyv;
            float px = (float)(t - 1 + k % 3) + oxv;
            float fy = floorf(py), fx = floorf(px);
            sy0[t] = (int)fy; sx0[t] = (int)fx;
            swy[t] = py - fy; swx[t] = px - fx;
        }
        for (int c0 = 0; c0 < 256; c0 += 16) {
            __syncthreads();
            const float* base = xn + ((c0 + cc_b) << 12);
#pragma unroll
            for (int u = 0; u < 4; ++u) {
                int p = p0_b + u;
                int y0 = sy0[p], x0 = sx0[p];
                float wy = swy[p], wx = swx[p];
                float v00 = 0.f, v01 = 0.f, v10 = 0.f, v11 = 0.f;
                bool oky0 = (unsigned)y0 < 64u, oky1 = (unsigned)(y0 + 1) < 64u;
                bool okx0 = (unsigned)x0 < 64u, okx1 = (unsigned)(x0 + 1) < 64u;
                int r0 = (y0 << 6) + x0;
                if (oky0 && okx0) v00 = base[r0];
                if (oky0 && okx1) v01 = base[r0 + 1];
                if (oky1 && okx0) v10 = base[r0 + 64];
                if (oky1 && okx1) v11 = base[r0 + 65];
                colS[cc_b][p] = (v00 * (1.f - wx) + v01 * wx) * (1.f - wy) +
                                (v10 * (1.f - wx) + v11 * wx) * wy;
            }
            const float* wt = w_t + (k << 16) + (c0 << 8) + co0;
#pragma unroll
            for (int i = 0; i < 2; ++i) {
                int fi = i * 256 + t;
                int cc = fi >> 5;
                int cf = (fi & 31) << 2;
                *(float4*)&wS[cc][cf] = *(const float4*)&wt[(cc << 8) + cf];
            }
            __syncthreads();
#pragma unroll
            for (int kk = 0; kk < 16; ++kk) {
                float4 cv = *(const float4*)&colS[kk][tp << 2];
                float4 w0 = *(const float4*)&wS[kk][tc << 3];
                float4 w1 = *(const float4*)&wS[kk][(tc << 3) + 4];
                float cva[4] = {cv.x, cv.y, cv.z, cv.w};
                float wa[8]  = {w0.x, w0.y, w0.z, w0.w, w1.x, w1.y, w1.z, w1.w};
#pragma unroll
                for (int i = 0; i < 4; ++i)
#pragma unroll
                    for (int j = 0; j < 8; ++j)
                        acc[i][j] = fmaf(cva[i], wa[j], acc[i][j]);
            }
        }
    }
    int ob = (n << 20) + ((co0 + (tc << 3)) << 12) + (h << 6) + (tp << 2);
#pragma unroll
    for (int j = 0; j < 8; ++j) {
        float4 v = {acc[0][j], acc[1][j], acc[2][j], acc[3][j]};
        *(float4*)&out[ob + (j << 12)] = v;
    }
}

extern "C" void kernel_launch(void* const* d_in, const int* in_sizes, int n_in,
                              void* d_out, int out_size, void* d_ws, size_t ws_size,
                              hipStream_t stream) {
    const float* x     = (const float*)d_in[0];
    const float* w_adj = (const float*)d_in[1];
    const float* b_adj = (const float*)d_in[2];
    const float* w_off = (const float*)d_in[3];
    const float* b_off = (const float*)d_in[4];
    const float* w_def = (const float*)d_in[5];
    float* out = (float*)d_out;

    char* ws = (char*)d_ws;
    float* xchan = (float*)ws;                          // 2359296 B
    float* off   = (float*)(ws + 2359296);              // 2359296 B

    k_xchan<<<1024, 256, 0, stream>>>(x, w_adj, b_adj, xchan);
    k_off<<<2304, 256, 0, stream>>>(xchan, w_off, b_off, off);

    const size_t NEED = 22675456;
    if (ws_size >= NEED) {
        ushort* wfrag = (ushort*)(ws + 4718592);        // 1179648 B
        ushort* xT    = (ushort*)(ws + 5898240);        // 16777216 B
        k_wfrag<<<2304, 256, 0, stream>>>(w_def, wfrag);
        k_trans<<<2048, 256, 0, stream>>>(x, xT);
        k_fused<<<1024, 256, 0, stream>>>(xT, off, wfrag, out);
    } else {
        float* w_t = (float*)(ws + 4718592);
        k_reorder<<<2304, 256, 0, stream>>>(w_def, w_t);
        k_deform<<<dim3(512, 2), 256, 0, stream>>>(x, off, w_t, out);
    }
}

// Round 11
// 95.920 us; speedup vs baseline: 5.6420x; 1.0938x over previous
//
#include <hip/hip_runtime.h>

// Sizes (fixed):
// x: (8,256,64,64) f32 | w_adj: (18,256,1,1) | b_adj: (18)
// w_off: (18,1,3,3) | b_off: (18) | w_def: (256,256,3,3)
// out: (8,256,64,64) f32
//
// Implicit GEMM: out[cout][pix] = sum_{K=tap*256+c} W[cout][K] * col[K][pix]
// M=256, N=32768, K=2304 -> 38.7 GFLOP -> bf16 MFMA.
// Round 11: (a) LDS XOR slot swizzle kills R10's 3.5M ds_write_b128 bank
// conflicts (write lanes 0-3 all hit bank-group 0); (b) v_cvt_pk_bf16_f32
// replaces 6-op manual RNE pack in interp; (c) xchan/wfrag/trans fused into
// one k_prep launch (independent; removes ~7us launch serialization).
//
// ws layout (bytes):
//   xchan f32 : [0,        2359296)
//   off   f32 : [2359296,  4718592)
//   wfrag bf16: [4718592,  5898240)
//   xT    bf16: [5898240,  22675456)    8n x 4096pix x 256c
// Fallback (ws too small): fp32 path, w_t f32 at [4718592, 7077888).

typedef __attribute__((ext_vector_type(8))) short short8v;
typedef __attribute__((ext_vector_type(4))) float f32x4;

#define NPLANE 4096

__device__ inline unsigned bf16_1(float a) {
    unsigned u = __float_as_uint(a);
    u += 0x7fffu + ((u >> 16) & 1u);
    return u >> 16;
}
__device__ inline unsigned bf16_pair(float a, float b) {
    unsigned ua = __float_as_uint(a); ua += 0x7fffu + ((ua >> 16) & 1u);
    unsigned ub = __float_as_uint(b); ub += 0x7fffu + ((ub >> 16) & 1u);
    return (ua >> 16) | (ub & 0xffff0000u);
}
__device__ inline unsigned cvt_pk(float lo, float hi) {   // HW RNE pack
    unsigned r;
    asm("v_cvt_pk_bf16_f32 %0, %1, %2" : "=v"(r) : "v"(lo), "v"(hi));
    return r;
}
__device__ inline float bl(unsigned u) { return __uint_as_float(u << 16); }
__device__ inline float bh(unsigned u) { return __uint_as_float(u & 0xffff0000u); }

// ---------------- fused prep: xchan (1024) | wfrag (2304) | trans (2048) ----
// Independent of each other; one launch of 5376 blocks.
__global__ __launch_bounds__(256) void k_prep(const float* __restrict__ x,
                                              const float* __restrict__ w_adj,
                                              const float* __restrict__ b_adj,
                                              const float* __restrict__ w_def,
                                              float* __restrict__ xchan,
                                              ushort* __restrict__ wfrag,
                                              ushort* __restrict__ xT) {
    __shared__ float wsh[256][18];
    __shared__ float part[8][32][19];
    __shared__ unsigned tileU[64][35];
    int b = blockIdx.x;
    int t = threadIdx.x;
    if (b < 1024) {
        // ---- 1x1 conv, split-K over 8 channel groups ----
        for (int i = t; i < 18 * 256; i += 256) {
            int o = i >> 8, c = i & 255;
            wsh[c][o] = w_adj[i];
        }
        __syncthreads();
        int n    = b >> 7;
        int pix0 = (b & 127) << 5;
        int p = t & 31, g = t >> 5;
        const float* xp = x + ((size_t)n << 20) + ((size_t)g << 17) + pix0 + p;
        float acc[18];
#pragma unroll
        for (int o = 0; o < 18; ++o) acc[o] = 0.f;
#pragma unroll 4
        for (int ci = 0; ci < 32; ++ci) {
            float xv = xp[(size_t)ci << 12];
            const float* wr = wsh[(g << 5) + ci];
#pragma unroll
            for (int o = 0; o < 18; ++o) acc[o] = fmaf(xv, wr[o], acc[o]);
        }
#pragma unroll
        for (int o = 0; o < 18; ++o) part[g][p][o] = acc[o];
        __syncthreads();
        for (int i = t; i < 576; i += 256) {
            int o = i >> 5, p2 = i & 31;
            float s = b_adj[o];
#pragma unroll
            for (int g2 = 0; g2 < 8; ++g2) s += part[g2][p2][o];
            xchan[((size_t)n * 18 + o) * NPLANE + pix0 + p2] = s;
        }
    } else if (b < 3328) {
        // ---- weight -> MFMA A-fragment layout ----
        int idx = (b - 1024) * 256 + t;
        int e     = idx & 7;
        int lane  = (idx >> 3) & 63;
        int ct    = (idx >> 9) & 15;
        int kstep = idx >> 13;
        int cout = ct * 16 + (lane & 15);
        int c    = ((kstep & 7) << 5) + ((lane >> 4) << 3) + e;
        int tap  = kstep >> 3;
        float v = w_def[cout * 2304 + c * 9 + tap];
        wfrag[idx] = (ushort)bf16_1(v);
    } else {
        // ---- transpose x -> xT bf16; XCD-aware (3328 % 8 == 0) ----
        int bb = b - 3328;
        int n  = bb & 7;
        int cg = (bb >> 3) & 3;
        int pg = bb >> 5;
        int pl = t & 63, c4 = t >> 6;
        const float* src = x + (((size_t)(n * 256 + cg * 64 + c4 * 16)) << 12)
                             + (pg << 6) + pl;
#pragma unroll
        for (int i2 = 0; i2 < 8; ++i2) {
            float f0 = src[(size_t)(2 * i2) << 12];
            float f1 = src[(size_t)(2 * i2 + 1) << 12];
            tileU[pl][c4 * 8 + i2] = bf16_pair(f0, f1);
        }
        __syncthreads();
        int cl2 = t & 31, pr = t >> 5;
        unsigned* dst = (unsigned*)xT;
#pragma unroll
        for (int i = 0; i < 8; ++i) {
            int p2 = pr + (i << 3);
            dst[((size_t)(n << 12) + (pg << 6) + p2) * 128 + (cg << 5) + cl2] =
                tileU[p2][cl2];
        }
    }
}

// ---------------- depthwise 3x3 (groups=18), pad=1 ----------------
__global__ __launch_bounds__(256) void k_off(const float* __restrict__ xchan,
                                             const float* __restrict__ w_off,
                                             const float* __restrict__ b_off,
                                             float* __restrict__ off) {
    int idx = blockIdx.x * 256 + threadIdx.x;
    int pix = idx & 4095;
    int w = pix & 63, h = pix >> 6;
    int rest = idx >> 12;
    int oc = rest % 18;
    const float* wp  = w_off + oc * 9;
    const float* src = xchan + (idx & ~4095);
    float acc = b_off[oc];
#pragma unroll
    for (int i = 0; i < 3; ++i) {
        int hh = h - 1 + i;
        if ((unsigned)hh >= 64u) continue;
#pragma unroll
        for (int j = 0; j < 3; ++j) {
            int ww = w - 1 + j;
            if ((unsigned)ww >= 64u) continue;
            acc = fmaf(src[(hh << 6) + ww], wp[i * 3 + j], acc);
        }
    }
    off[idx] = acc;
}

// ---------------- fused sampler + MFMA GEMM ----------------
// grid = 1024: n = b&7 (XCD), tq = b>>3 (0..127, 32-px tile).
// block = 4 waves; GEMM role: wave wv -> couttiles [4wv,4wv+4), acc[2][4].
// Sampling role: ksp = t>>7, tile = (t>>6)&1, pix = (t>>2)&15, cg = t&3
//   (wave = 16px x 4cg -> 4 cgs of a corner share one 64B line).
// LDS slot XOR swizzle: logical slot s=(hi<<4)|lo stored at (hi<<4)|(lo^2hi)
//   -> ds_write (cg-major lanes) AND ds_read (linear lanes) both hit 8
//   distinct bank-groups per 8-lane phase. (R10: write was 4-way, 3.5M cyc.)
__global__ __launch_bounds__(256) void k_fused(const ushort* __restrict__ xT,
                                               const float* __restrict__ off,
                                               const ushort* __restrict__ wfrag,
                                               float* __restrict__ out) {
    __shared__ __align__(16) ushort colS[2][2][2][64][8];   // 8 KB: buf/ksp/tile/slot/e

    int t = threadIdx.x;
    int wv = t >> 6, lane = t & 63;
    int n  = blockIdx.x & 7;
    int tq = blockIdx.x >> 3;

    // sampling role
    int ksp  = t >> 7;               // kstep parity within batch
    int tile = (t >> 6) & 1;         // pixtile
    int pix  = (t >> 2) & 15;        // pixel within tile
    int cg   = t & 3;                // channel group (8 ch)
    int sc   = cg << 3;
    int spix = (tq << 5) + (tile << 4) + pix;
    int sy = spix >> 6, sx = spix & 63;

    const float* offn = off + (((size_t)n * 18) << 12) + spix;
    const ushort* xTn = xT + (((size_t)n) << 12) * 256;

    // swizzled LDS write slot (logical s = (cg<<4)+pix)
    int wslot = (cg << 4) | ((pix ^ (cg << 1)) & 15);
    ushort* wp0 = &colS[0][ksp][tile][wslot][0];
    ushort* wp1 = &colS[1][ksp][tile][wslot][0];

    float w00, w01, w10, w11;
    unsigned oA, oB, oC, oD;     // element offsets into xTn (include sc)

    auto tap_setup = [&](int tp) {
        float oyv = offn[(size_t)(2 * tp) << 12];
        float oxv = offn[(size_t)(2 * tp + 1) << 12];
        int trow = (tp * 11) >> 5;           // tp/3 for 0..8
        int tcol = tp - trow * 3;
        float py = (float)(sy - 1 + trow) + oyv;
        float px = (float)(sx - 1 + tcol) + oxv;
        float fy = floorf(py), fx = floorf(px);
        int y0 = (int)fy, x0 = (int)fx;
        float wy1 = py - fy, wx1 = px - fx;
        float ay0 = ((unsigned)y0       < 64u) ? 1.f - wy1 : 0.f;
        float ay1 = ((unsigned)(y0 + 1) < 64u) ? wy1 : 0.f;
        float ax0 = ((unsigned)x0       < 64u) ? 1.f - wx1 : 0.f;
        float ax1 = ((unsigned)(x0 + 1) < 64u) ? wx1 : 0.f;
        w00 = ay0 * ax0; w01 = ay0 * ax1; w10 = ay1 * ax0; w11 = ay1 * ax1;
        int yc0 = min(max(y0, 0), 63), yc1 = min(max(y0 + 1, 0), 63);
        int xc0 = min(max(x0, 0), 63), xc1 = min(max(x0 + 1, 0), 63);
        oA = (unsigned)((((yc0 << 6) + xc0) << 8) + sc);
        oB = (unsigned)((((yc0 << 6) + xc1) << 8) + sc);
        oC = (unsigned)((((yc1 << 6) + xc0) << 8) + sc);
        oD = (unsigned)((((yc1 << 6) + xc1) << 8) + sc);
    };

    // gather set (register-resident across one batch)
    uint4 gA, gB, gC, gD;
    auto issue = [&](int m) {    // gathers for batch m (thread's kstep 2m+ksp)
        unsigned dd = (unsigned)(((2 * m + ksp) & 7) << 5);
        gA = *(const uint4*)(xTn + oA + dd);
        gB = *(const uint4*)(xTn + oB + dd);
        gC = *(const uint4*)(xTn + oC + dd);
        gD = *(const uint4*)(xTn + oD + dd);
    };
    auto interp_to = [&](ushort* wp) {
        unsigned qa[4] = {gA.x, gA.y, gA.z, gA.w};
        unsigned qb[4] = {gB.x, gB.y, gB.z, gB.w};
        unsigned qc[4] = {gC.x, gC.y, gC.z, gC.w};
        unsigned qd[4] = {gD.x, gD.y, gD.z, gD.w};
        unsigned rr[4];
#pragma unroll
        for (int i = 0; i < 4; ++i) {
            float v0 = w00 * bl(qa[i]) + w01 * bl(qb[i]) +
                       w10 * bl(qc[i]) + w11 * bl(qd[i]);
            float v1 = w00 * bh(qa[i]) + w01 * bh(qb[i]) +
                       w10 * bh(qc[i]) + w11 * bh(qd[i]);
            rr[i] = cvt_pk(v0, v1);
        }
        *(uint4*)wp = make_uint4(rr[0], rr[1], rr[2], rr[3]);
    };

    f32x4 acc[2][4] = {};
    const int ctb = wv << 2;     // wave's base couttile

    short8v bbA[4], bbB[4], bbN[4];
    auto loadW = [&](int ks, short8v* dst) {
        const ushort* wb = wfrag + ((size_t)ks * 16 + ctb) * 512 + (lane << 3);
#pragma unroll
        for (int j = 0; j < 4; ++j)
            dst[j] = *(const short8v*)(wb + (size_t)j * 512);
    };

    // swizzled read slots (logical slot = lane)
    const int rslot = ((lane >> 4) << 4) | ((lane & 15) ^ ((lane >> 4) << 1));

    // ---- prologue: batch 0 -> buf0; gathers for batch 1; W(0) -> bbA ----
    tap_setup(0);
    issue(0);
    interp_to(wp0);
    issue(1);                    // batch 1 = ksteps 2,3 (still tap 0)
    loadW(0, bbA);
    __syncthreads();

    // ---- main loop: 36 batches (72 ksteps), 2x unrolled for static ph ----
    for (int bt2 = 0; bt2 < 18; ++bt2) {
#pragma unroll
        for (int ph = 0; ph < 2; ++ph) {
            const int bt = bt2 * 2 + ph;
            // (0) ds_read A-frags for this batch from buf[ph]
            const ushort* rb = &colS[ph][0][0][0][0];
            short8v a00 = *(const short8v*)(rb + ((0 * 64 + rslot) << 3));
            short8v a01 = *(const short8v*)(rb + ((1 * 64 + rslot) << 3));
            short8v a10 = *(const short8v*)(rb + ((2 * 64 + rslot) << 3));
            short8v a11 = *(const short8v*)(rb + ((3 * 64 + rslot) << 3));
            // (1) weight loads early (L2 latency hides behind interp + MFMA)
            loadW(2 * bt + 1, bbB);
            if (bt + 1 < 36) loadW(2 * bt + 2, bbN);
            // (2) interp gathers (batch bt+1) -> buf[ph^1]   [VALU]
            if (bt + 1 < 36) interp_to(ph ? wp0 : wp1);
            // (3) issue gathers for batch bt+2
            if (bt + 2 < 36) {
                if (((bt + 2) & 3) == 0) tap_setup((bt + 2) >> 2);
                issue(bt + 2);
            }
            // (4) MFMA: kstep 2bt with bbA, kstep 2bt+1 with bbB
#pragma unroll
            for (int j = 0; j < 4; ++j) {
                acc[0][j] = __builtin_amdgcn_mfma_f32_16x16x32_bf16(
                    bbA[j], a00, acc[0][j], 0, 0, 0);
                acc[1][j] = __builtin_amdgcn_mfma_f32_16x16x32_bf16(
                    bbA[j], a01, acc[1][j], 0, 0, 0);
            }
#pragma unroll
            for (int j = 0; j < 4; ++j) {
                acc[0][j] = __builtin_amdgcn_mfma_f32_16x16x32_bf16(
                    bbB[j], a10, acc[0][j], 0, 0, 0);
                acc[1][j] = __builtin_amdgcn_mfma_f32_16x16x32_bf16(
                    bbB[j], a11, acc[1][j], 0, 0, 0);
            }
            // (5) barrier: buf[ph^1] writes done, buf[ph] reads done
            __syncthreads();
#pragma unroll
            for (int j = 0; j < 4; ++j) bbA[j] = bbN[j];
        }
    }

    // epilogue: D layout col = lane&15 (pix), row = (lane>>4)*4 + r (cout)
    int cl = lane & 15;
    int ch = (lane >> 4) << 2;
    float* outn = out + ((size_t)n << 20);
#pragma unroll
    for (int i = 0; i < 2; ++i) {
        int opix = (tq << 5) + (i << 4) + cl;
#pragma unroll
        for (int j = 0; j < 4; ++j) {
            int cout = ((ctb + j) << 4) + ch;
            float* op = outn + ((size_t)cout << 12) + opix;
#pragma unroll
            for (int rr = 0; rr < 4; ++rr) op[(size_t)rr << 12] = acc[i][j][rr];
        }
    }
}

// ================= fallback fp32 path (ws too small) =================
__global__ __launch_bounds__(256) void k_xchan(const float* __restrict__ x,
                                               const float* __restrict__ w_adj,
                                               const float* __restrict__ b_adj,
                                               float* __restrict__ xchan) {
    __shared__ float wsh[256][18];
    __shared__ float part[8][32][19];
    int t = threadIdx.x;
    for (int i = t; i < 18 * 256; i += 256) {
        int o = i >> 8, c = i & 255;
        wsh[c][o] = w_adj[i];
    }
    __syncthreads();
    int n    = blockIdx.x >> 7;
    int pix0 = (blockIdx.x & 127) << 5;
    int p = t & 31, g = t >> 5;
    const float* xp = x + ((size_t)n << 20) + ((size_t)g << 17) + pix0 + p;
    float acc[18];
#pragma unroll
    for (int o = 0; o < 18; ++o) acc[o] = 0.f;
#pragma unroll 4
    for (int ci = 0; ci < 32; ++ci) {
        float xv = xp[(size_t)ci << 12];
        const float* wr = wsh[(g << 5) + ci];
#pragma unroll
        for (int o = 0; o < 18; ++o) acc[o] = fmaf(xv, wr[o], acc[o]);
    }
#pragma unroll
    for (int o = 0; o < 18; ++o) part[g][p][o] = acc[o];
    __syncthreads();
    for (int i = t; i < 576; i += 256) {
        int o = i >> 5, p2 = i & 31;
        float s = b_adj[o];
#pragma unroll
        for (int g2 = 0; g2 < 8; ++g2) s += part[g2][p2][o];
        xchan[((size_t)n * 18 + o) * NPLANE + pix0 + p2] = s;
    }
}

__global__ __launch_bounds__(256) void k_reorder(const float* __restrict__ w_def,
                                                 float* __restrict__ w_t) {
    int idx = blockIdx.x * 256 + threadIdx.x;
    int co = idx & 255;
    int c  = (idx >> 8) & 255;
    int k  = idx >> 16;
    w_t[idx] = w_def[co * 2304 + c * 9 + k];
}

__global__ __launch_bounds__(256) void k_deform(const float* __restrict__ x,
                                                const float* __restrict__ off,
                                                const float* __restrict__ w_t,
                                                float* __restrict__ out) {
    __shared__ float colS[16][64];
    __shared__ float wS[16][128];
    __shared__ int   sy0[64], sx0[64];
    __shared__ float swy[64], swx[64];
    int t   = threadIdx.x;
    int n   = blockIdx.x >> 6;
    int h   = blockIdx.x & 63;
    int co0 = blockIdx.y << 7;
    float acc[4][8];
#pragma unroll
    for (int i = 0; i < 4; ++i)
#pragma unroll
        for (int j = 0; j < 8; ++j) acc[i][j] = 0.f;
    int tp = t & 15, tc = t >> 4;
    int cc_b = t >> 4, p0_b = (t & 15) << 2;
    const float* xn = x + (n << 20);
    for (int k = 0; k < 9; ++k) {
        if (t < 64) {
            const float* offp = off + ((n * 18 + 2 * k) << 12) + (h << 6);
            float oyv = offp[t];
            float oxv = offp[4096 + t];
            float py = (float)(h - 1 + k / 3) + oyv;
            float px = (float)(t - 1 + k % 3) + oxv;
            float fy = floorf(py), fx = floorf(px);
            sy0[t] = (int)fy; sx0[t] = (int)fx;
            swy[t] = py - fy; swx[t] = px - fx;
        }
        for (int c0 = 0; c0 < 256; c0 += 16) {
            __syncthreads();
            const float* base = xn + ((c0 + cc_b) << 12);
#pragma unroll
            for (int u = 0; u < 4; ++u) {
                int p = p0_b + u;
                int y0 = sy0[p], x0 = sx0[p];
                float wy = swy[p], wx = swx[p];
                float v00 = 0.f, v01 = 0.f, v10 = 0.f, v11 = 0.f;
                bool oky0 = (unsigned)y0 < 64u, oky1 = (unsigned)(y0 + 1) < 64u;
                bool okx0 = (unsigned)x0 < 64u, okx1 = (unsigned)(x0 + 1) < 64u;
                int r0 = (y0 << 6) + x0;
                if (oky0 && okx0) v00 = base[r0];
                if (oky0 && okx1) v01 = base[r0 + 1];
                if (oky1 && okx0) v10 = base[r0 + 64];
                if (oky1 && okx1) v11 = base[r0 + 65];
                colS[cc_b][p] = (v00 * (1.f - wx) + v01 * wx) * (1.f - wy) +
                                (v10 * (1.f - wx) + v11 * wx) * wy;
            }
            const float* wt = w_t + (k << 16) + (c0 << 8) + co0;
#pragma unroll
            for (int i = 0; i < 2; ++i) {
                int fi = i * 256 + t;
                int cc = fi >> 5;
                int cf = (fi & 31) << 2;
                *(float4*)&wS[cc][cf] = *(const float4*)&wt[(cc << 8) + cf];
            }
            __syncthreads();
#pragma unroll
            for (int kk = 0; kk < 16; ++kk) {
                float4 cv = *(const float4*)&colS[kk][tp << 2];
                float4 w0 = *(const float4*)&wS[kk][tc << 3];
                float4 w1 = *(const float4*)&wS[kk][(tc << 3) + 4];
                float cva[4] = {cv.x, cv.y, cv.z, cv.w};
                float wa[8]  = {w0.x, w0.y, w0.z, w0.w, w1.x, w1.y, w1.z, w1.w};
#pragma unroll
                for (int i = 0; i < 4; ++i)
#pragma unroll
                    for (int j = 0; j < 8; ++j)
                        acc[i][j] = fmaf(cva[i], wa[j], acc[i][j]);
            }
        }
    }
    int ob = (n << 20) + ((co0 + (tc << 3)) << 12) + (h << 6) + (tp << 2);
#pragma unroll
    for (int j = 0; j < 8; ++j) {
        float4 v = {acc[0][j], acc[1][j], acc[2][j], acc[3][j]};
        *(float4*)&out[ob + (j << 12)] = v;
    }
}

extern "C" void kernel_launch(void* const* d_in, const int* in_sizes, int n_in,
                              void* d_out, int out_size, void* d_ws, size_t ws_size,
                              hipStream_t stream) {
    const float* x     = (const float*)d_in[0];
    const float* w_adj = (const float*)d_in[1];
    const float* b_adj = (const float*)d_in[2];
    const float* w_off = (const float*)d_in[3];
    const float* b_off = (const float*)d_in[4];
    const float* w_def = (const float*)d_in[5];
    float* out = (float*)d_out;

    char* ws = (char*)d_ws;
    float* xchan = (float*)ws;                          // 2359296 B
    float* off   = (float*)(ws + 2359296);              // 2359296 B

    const size_t NEED = 22675456;
    if (ws_size >= NEED) {
        ushort* wfrag = (ushort*)(ws + 4718592);        // 1179648 B
        ushort* xT    = (ushort*)(ws + 5898240);        // 16777216 B
        k_prep<<<5376, 256, 0, stream>>>(x, w_adj, b_adj, w_def,
                                         xchan, wfrag, xT);
        k_off<<<2304, 256, 0, stream>>>(xchan, w_off, b_off, off);
        k_fused<<<1024, 256, 0, stream>>>(xT, off, wfrag, out);
    } else {
        float* w_t = (float*)(ws + 4718592);
        k_xchan<<<1024, 256, 0, stream>>>(x, w_adj, b_adj, xchan);
        k_off<<<2304, 256, 0, stream>>>(xchan, w_off, b_off, off);
        k_reorder<<<2304, 256, 0, stream>>>(w_def, w_t);
        k_deform<<<dim3(512, 2), 256, 0, stream>>>(x, off, w_t, out);
    }
}